// Round 1
// baseline (2138.014 us; speedup 1.0000x reference)
//
#include <hip/hip_runtime.h>
#include <math.h>

#define Dm 1024
#define Tn 1024
#define Bn 2
#define NTOK 2048
#define HQn 16
#define HKVn 4
#define KDn 64
#define VDn 64
#define Gn 4
#define NE 8
#define CAPn 1024
#define HIDn 2048

// ---------------- RMSNorm ----------------
__global__ void rmsnorm_kernel(const float* __restrict__ x, const float* __restrict__ scale,
                               float* __restrict__ out) {
    int row = blockIdx.x;
    const float* xr = x + (size_t)row * Dm;
    float ss = 0.f;
    for (int d = threadIdx.x; d < Dm; d += 256) { float v = xr[d]; ss += v * v; }
    __shared__ float red[256];
    red[threadIdx.x] = ss; __syncthreads();
    for (int s = 128; s > 0; s >>= 1) {
        if (threadIdx.x < s) red[threadIdx.x] += red[threadIdx.x + s];
        __syncthreads();
    }
    float inv = rsqrtf(red[0] * (1.f / Dm) + 1e-6f);
    for (int d = threadIdx.x; d < Dm; d += 256)
        out[(size_t)row * Dm + d] = xr[d] * inv * scale[d];
}

// ---------------- Generic fp32 tiled GEMM: C = A@B (+R) ----------------
// 64x64 tile, BK=16, 256 threads, 4x4 per thread. M,N mult of 64; K mult of 16.
template<int MODE>  // 0: C=AB   1: C=AB+R
__global__ void gemm64(const float* __restrict__ A, const float* __restrict__ Bm,
                       const float* __restrict__ R, float* __restrict__ C,
                       int M, int N, int K) {
    __shared__ float As[16][68];
    __shared__ float Bs[16][68];
    int tid = threadIdx.x;
    int tx = tid & 15, ty = tid >> 4;
    int arow = blockIdx.y * 64, bcol = blockIdx.x * 64;
    float acc[4][4] = {};
    for (int kk = 0; kk < K; kk += 16) {
        int am = tid >> 2, ak = (tid & 3) * 4;
        float4 a4 = *(const float4*)(A + (size_t)(arow + am) * K + kk + ak);
        As[ak + 0][am] = a4.x; As[ak + 1][am] = a4.y; As[ak + 2][am] = a4.z; As[ak + 3][am] = a4.w;
        int bk = tid >> 4, bn = (tid & 15) * 4;
        *(float4*)&Bs[bk][bn] = *(const float4*)(Bm + (size_t)(kk + bk) * N + bcol + bn);
        __syncthreads();
        #pragma unroll
        for (int k = 0; k < 16; ++k) {
            float4 av = *(float4*)&As[k][ty * 4];
            float4 bv = *(float4*)&Bs[k][tx * 4];
            float a[4] = {av.x, av.y, av.z, av.w};
            float b[4] = {bv.x, bv.y, bv.z, bv.w};
            #pragma unroll
            for (int i = 0; i < 4; ++i)
                #pragma unroll
                for (int j = 0; j < 4; ++j)
                    acc[i][j] += a[i] * b[j];
        }
        __syncthreads();
    }
    #pragma unroll
    for (int i = 0; i < 4; ++i)
        #pragma unroll
        for (int j = 0; j < 4; ++j) {
            int m = arow + ty * 4 + i, n = bcol + tx * 4 + j;
            float v = acc[i][j];
            if (MODE == 1) v += R[(size_t)m * N + n];
            C[(size_t)m * N + n] = v;
        }
}

// ---------------- RoPE (in place) ----------------
__global__ void rope_kernel(float* __restrict__ p, int H, int total) {
    int idx = blockIdx.x * 256 + threadIdx.x;
    if (idx >= total) return;
    int i = idx & 31;
    int h = (idx >> 5) % H;
    int row = idx / (H * 32);
    int t = row & (Tn - 1);
    size_t base = ((size_t)row * H + h) * 64;
    float theta = __expf(-(float)i * (1.f / 32.f) * 9.210340371976184f); // 10000^(-i/32)
    float ang = (float)t * theta;
    float c = cosf(ang), s = sinf(ang);
    float x1 = p[base + i], x2 = p[base + i + 32];
    p[base + i]      = x1 * c - x2 * s;
    p[base + i + 32] = x2 * c + x1 * s;
}

// ---------------- Attention (two-pass per (b,h,tq) row) ----------------
__global__ void attn_kernel(const float* __restrict__ q, const float* __restrict__ k,
                            const float* __restrict__ v, float* __restrict__ attn) {
    int tq = blockIdx.x, h = blockIdx.y, b = blockIdx.z;
    int kvh = h >> 2; // G=4
    __shared__ float qs[KDn];
    __shared__ float p[Tn];
    __shared__ float red[256];
    int tid = threadIdx.x;
    const float* qrow = q + (((size_t)(b * Tn + tq)) * HQn + h) * KDn;
    if (tid < KDn) qs[tid] = qrow[tid];
    __syncthreads();
    float lmax = -1e30f;
    for (int s = tid; s <= tq; s += 256) {
        const float* kr = k + (((size_t)(b * Tn + s)) * HKVn + kvh) * KDn;
        float dot = 0.f;
        #pragma unroll
        for (int d = 0; d < KDn; d += 4) {
            float4 k4 = *(const float4*)(kr + d);
            dot += qs[d] * k4.x + qs[d + 1] * k4.y + qs[d + 2] * k4.z + qs[d + 3] * k4.w;
        }
        dot *= 0.125f;
        p[s] = dot;
        lmax = fmaxf(lmax, dot);
    }
    red[tid] = lmax; __syncthreads();
    for (int s2 = 128; s2; s2 >>= 1) { if (tid < s2) red[tid] = fmaxf(red[tid], red[tid + s2]); __syncthreads(); }
    float m = red[0]; __syncthreads();
    float lsum = 0.f;
    for (int s = tid; s <= tq; s += 256) { float ev = __expf(p[s] - m); p[s] = ev; lsum += ev; }
    red[tid] = lsum; __syncthreads();
    for (int s2 = 128; s2; s2 >>= 1) { if (tid < s2) red[tid] += red[tid + s2]; __syncthreads(); }
    float inv = 1.f / red[0]; __syncthreads();
    int dv = tid & 63, qtr = tid >> 6;
    int len = tq + 1;
    int chunk = (len + 3) >> 2;
    int s0 = qtr * chunk, s1 = min(s0 + chunk, len);
    float o = 0.f;
    for (int s = s0; s < s1; ++s)
        o += p[s] * v[(((size_t)(b * Tn + s)) * HKVn + kvh) * VDn + dv];
    red[tid] = o; __syncthreads();
    if (tid < 64) {
        float sum = red[tid] + red[tid + 64] + red[tid + 128] + red[tid + 192];
        attn[((size_t)(b * Tn + tq)) * (HQn * VDn) + h * VDn + tid] = sum * inv;
    }
}

// ---------------- Router: logits + top2 + gates ----------------
__global__ void router_kernel(const float* __restrict__ h2, const float* __restrict__ rw,
                              const float* __restrict__ rb, int* __restrict__ assign,
                              float* __restrict__ gate) {
    int t = blockIdx.x;
    __shared__ float row[Dm];
    __shared__ float logits[NE];
    for (int d = threadIdx.x; d < Dm; d += 512) row[d] = h2[(size_t)t * Dm + d];
    __syncthreads();
    int e = threadIdx.x >> 6, lane = threadIdx.x & 63;
    float part = 0.f;
    for (int d = lane; d < Dm; d += 64) part += row[d] * rw[(size_t)d * NE + e];
    for (int off = 32; off; off >>= 1) part += __shfl_down(part, off);
    if (lane == 0) logits[e] = part + rb[e];
    __syncthreads();
    if (threadIdx.x == 0) {
        int i0 = 0; float m0 = logits[0];
        for (int i = 1; i < NE; ++i) if (logits[i] > m0) { m0 = logits[i]; i0 = i; }
        int i1 = -1; float m1 = -1e30f;
        for (int i = 0; i < NE; ++i) if (i != i0 && logits[i] > m1) { m1 = logits[i]; i1 = i; }
        float e1 = __expf(m1 - m0);
        float s = 1.f + e1;
        assign[t * 2] = i0; assign[t * 2 + 1] = i1;
        gate[t * 2] = 1.f / s; gate[t * 2 + 1] = e1 / s;
    }
}

// ---------------- Capacity scan (single block) ----------------
// pos[t,0] = inclusive prefix of slot-0 count for its expert.
// pos[t,1] = inclusive slot-0 prefix + inclusive slot-1 prefix for its expert.
__global__ void scan_kernel(const int* __restrict__ assign, int* __restrict__ pos,
                            int* __restrict__ limit) {
    __shared__ int cnt[256][16];
    __shared__ int tot[16];
    int tid = threadIdx.x;
    int local[16];
    #pragma unroll
    for (int i = 0; i < 16; ++i) local[i] = 0;
    for (int r = 0; r < 8; ++r) {
        int t = tid * 8 + r;
        local[assign[t * 2]]++;
        local[8 + assign[t * 2 + 1]]++;
    }
    #pragma unroll
    for (int i = 0; i < 16; ++i) cnt[tid][i] = local[i];
    __syncthreads();
    if (tid < 16) {
        int run = 0;
        for (int th = 0; th < 256; ++th) { int v = cnt[th][tid]; cnt[th][tid] = run; run += v; }
        tot[tid] = run;
    }
    __syncthreads();
    int r0[NE], r1[NE];
    #pragma unroll
    for (int e = 0; e < NE; ++e) { r0[e] = cnt[tid][e]; r1[e] = cnt[tid][8 + e]; }
    for (int r = 0; r < 8; ++r) {
        int t = tid * 8 + r;
        int e0 = assign[t * 2], e1 = assign[t * 2 + 1];
        r0[e0]++; pos[t * 2] = r0[e0];
        r1[e1]++; pos[t * 2 + 1] = r0[e1] + r1[e1];
    }
    if (tid == 0)
        for (int e = 0; e < NE; ++e) {
            int C = tot[e] + tot[8 + e];
            limit[e] = C < (CAPn - 1) ? C : (CAPn - 1);
        }
}

// ---------------- Dispatch (scatter-add; collisions sum per reference) ----------------
__global__ void dispatch_kernel(const float* __restrict__ h2, const int* __restrict__ assign,
                                const int* __restrict__ pos, float* __restrict__ grouped) {
    int slot = blockIdx.x; // t*2+j
    int p = pos[slot];
    if (p >= CAPn) return;
    int e = assign[slot];
    const float* src = h2 + (size_t)(slot >> 1) * Dm;
    float* dst = grouped + ((size_t)e * CAPn + p) * Dm;
    for (int d = threadIdx.x; d < Dm; d += 256) atomicAdd(&dst[d], src[d]);
}

__device__ __forceinline__ float gelu_tanh(float y) {
    return 0.5f * y * (1.f + tanhf(0.7978845608028654f * (y + 0.044715f * y * y * y)));
}

// ---------------- Expert FFN stage 1: hh = gelu((A@w2)*(A@w1)) ----------------
__global__ void ffn1_gemm(const float* __restrict__ grouped, const float* __restrict__ w1,
                          const float* __restrict__ w2, float* __restrict__ hh,
                          const int* __restrict__ limit) {
    int e = blockIdx.z;
    if ((int)(blockIdx.y * 64) > limit[e]) return;
    const float* A  = grouped + (size_t)e * CAPn * Dm;
    const float* B1 = w1 + (size_t)e * Dm * HIDn;
    const float* B2 = w2 + (size_t)e * Dm * HIDn;
    float* C = hh + (size_t)e * CAPn * HIDn;
    __shared__ float As[16][68];
    __shared__ float Bs1[16][68];
    __shared__ float Bs2[16][68];
    int tid = threadIdx.x;
    int tx = tid & 15, ty = tid >> 4;
    int arow = blockIdx.y * 64, bcol = blockIdx.x * 64;
    float acc1[4][4] = {}, acc2[4][4] = {};
    for (int kk = 0; kk < Dm; kk += 16) {
        int am = tid >> 2, ak = (tid & 3) * 4;
        float4 a4 = *(const float4*)(A + (size_t)(arow + am) * Dm + kk + ak);
        As[ak + 0][am] = a4.x; As[ak + 1][am] = a4.y; As[ak + 2][am] = a4.z; As[ak + 3][am] = a4.w;
        int bk = tid >> 4, bn = (tid & 15) * 4;
        *(float4*)&Bs1[bk][bn] = *(const float4*)(B1 + (size_t)(kk + bk) * HIDn + bcol + bn);
        *(float4*)&Bs2[bk][bn] = *(const float4*)(B2 + (size_t)(kk + bk) * HIDn + bcol + bn);
        __syncthreads();
        #pragma unroll
        for (int k = 0; k < 16; ++k) {
            float4 av = *(float4*)&As[k][ty * 4];
            float4 b1 = *(float4*)&Bs1[k][tx * 4];
            float4 b2 = *(float4*)&Bs2[k][tx * 4];
            float a[4] = {av.x, av.y, av.z, av.w};
            float v1[4] = {b1.x, b1.y, b1.z, b1.w};
            float v2[4] = {b2.x, b2.y, b2.z, b2.w};
            #pragma unroll
            for (int i = 0; i < 4; ++i)
                #pragma unroll
                for (int j = 0; j < 4; ++j) {
                    acc1[i][j] += a[i] * v1[j];
                    acc2[i][j] += a[i] * v2[j];
                }
        }
        __syncthreads();
    }
    #pragma unroll
    for (int i = 0; i < 4; ++i)
        #pragma unroll
        for (int j = 0; j < 4; ++j) {
            int m = arow + ty * 4 + i, n = bcol + tx * 4 + j;
            C[(size_t)m * HIDn + n] = gelu_tanh(acc2[i][j] * acc1[i][j]);
        }
}

// ---------------- Expert FFN stage 2: eout = hh @ w3 ----------------
__global__ void ffn2_gemm(const float* __restrict__ hh, const float* __restrict__ w3,
                          float* __restrict__ eout, const int* __restrict__ limit) {
    int e = blockIdx.z;
    if ((int)(blockIdx.y * 64) > limit[e]) return;
    const float* A = hh + (size_t)e * CAPn * HIDn;
    const float* Bm = w3 + (size_t)e * HIDn * Dm;
    float* C = eout + (size_t)e * CAPn * Dm;
    __shared__ float As[16][68];
    __shared__ float Bs[16][68];
    int tid = threadIdx.x;
    int tx = tid & 15, ty = tid >> 4;
    int arow = blockIdx.y * 64, bcol = blockIdx.x * 64;
    float acc[4][4] = {};
    for (int kk = 0; kk < HIDn; kk += 16) {
        int am = tid >> 2, ak = (tid & 3) * 4;
        float4 a4 = *(const float4*)(A + (size_t)(arow + am) * HIDn + kk + ak);
        As[ak + 0][am] = a4.x; As[ak + 1][am] = a4.y; As[ak + 2][am] = a4.z; As[ak + 3][am] = a4.w;
        int bk = tid >> 4, bn = (tid & 15) * 4;
        *(float4*)&Bs[bk][bn] = *(const float4*)(Bm + (size_t)(kk + bk) * Dm + bcol + bn);
        __syncthreads();
        #pragma unroll
        for (int k = 0; k < 16; ++k) {
            float4 av = *(float4*)&As[k][ty * 4];
            float4 bv = *(float4*)&Bs[k][tx * 4];
            float a[4] = {av.x, av.y, av.z, av.w};
            float b[4] = {bv.x, bv.y, bv.z, bv.w};
            #pragma unroll
            for (int i = 0; i < 4; ++i)
                #pragma unroll
                for (int j = 0; j < 4; ++j)
                    acc[i][j] += a[i] * b[j];
        }
        __syncthreads();
    }
    #pragma unroll
    for (int i = 0; i < 4; ++i)
        #pragma unroll
        for (int j = 0; j < 4; ++j) {
            int m = arow + ty * 4 + i, n = bcol + tx * 4 + j;
            C[(size_t)m * Dm + n] = acc[i][j];
        }
}

// ---------------- Combine ----------------
__global__ void combine_kernel(const float* __restrict__ x2, const float* __restrict__ h2,
                               const float* __restrict__ eout, const int* __restrict__ assign,
                               const int* __restrict__ pos, const float* __restrict__ gate,
                               float* __restrict__ out) {
    int t = blockIdx.x;
    int e0 = assign[t * 2], e1 = assign[t * 2 + 1];
    int p0 = pos[t * 2],   p1 = pos[t * 2 + 1];
    float g0 = gate[t * 2], g1 = gate[t * 2 + 1];
    const float* src0 = (p0 < CAPn) ? eout + ((size_t)e0 * CAPn + p0) * Dm : h2 + (size_t)t * Dm;
    const float* src1 = (p1 < CAPn) ? eout + ((size_t)e1 * CAPn + p1) * Dm : h2 + (size_t)t * Dm;
    for (int d = threadIdx.x; d < Dm; d += 256)
        out[(size_t)t * Dm + d] = x2[(size_t)t * Dm + d] + g0 * src0[d] + g1 * src1[d];
}

extern "C" void kernel_launch(void* const* d_in, const int* in_sizes, int n_in,
                              void* d_out, int out_size, void* d_ws, size_t ws_size,
                              hipStream_t stream) {
    const float* x        = (const float*)d_in[0];
    const float* wq       = (const float*)d_in[1];
    const float* wk       = (const float*)d_in[2];
    const float* wv       = (const float*)d_in[3];
    const float* wo       = (const float*)d_in[4];
    const float* router_w = (const float*)d_in[5];
    const float* router_b = (const float*)d_in[6];
    const float* w1       = (const float*)d_in[7];
    const float* w2       = (const float*)d_in[8];
    const float* w3       = (const float*)d_in[9];
    const float* n1s      = (const float*)d_in[10];
    const float* n2s      = (const float*)d_in[11];
    float* out = (float*)d_out;
    unsigned char* ws = (unsigned char*)d_ws;
    const size_t MB = 1ull << 20;

    // Workspace layout (timeline-aliased):
    //   [0,28M):  h, q, k, v, attn   (dead before MoE FFN)
    //   [0,64M):  hh                 (written/read in FFN stages only)
    //   [64,72M): x2   [72,80M): h2  [80,81M): router small buffers
    //   [81,113M): grouped, then aliased by eout (grouped dead after ffn1)
    float* h       = (float*)(ws + 0 * MB);
    float* q       = (float*)(ws + 8 * MB);
    float* kbuf    = (float*)(ws + 16 * MB);
    float* vbuf    = (float*)(ws + 18 * MB);
    float* attnbuf = (float*)(ws + 20 * MB);
    float* hh      = (float*)(ws + 0 * MB);
    float* x2      = (float*)(ws + 64 * MB);
    float* h2      = (float*)(ws + 72 * MB);
    int*   assign  = (int*)  (ws + 80 * MB);
    int*   pos     = (int*)  (ws + 80 * MB + 65536);
    float* gate    = (float*)(ws + 80 * MB + 131072);
    int*   limit   = (int*)  (ws + 80 * MB + 196608);
    float* grouped = (float*)(ws + 81 * MB);
    float* eout    = (float*)(ws + 81 * MB);
    (void)in_sizes; (void)n_in; (void)out_size; (void)ws_size;

    // 1. norm1
    rmsnorm_kernel<<<NTOK, 256, 0, stream>>>(x, n1s, h);
    // 2-4. QKV projections
    gemm64<0><<<dim3(Dm / 64, NTOK / 64), 256, 0, stream>>>(h, wq, nullptr, q, NTOK, Dm, Dm);
    gemm64<0><<<dim3((HKVn * KDn) / 64, NTOK / 64), 256, 0, stream>>>(h, wk, nullptr, kbuf, NTOK, HKVn * KDn, Dm);
    gemm64<0><<<dim3((HKVn * VDn) / 64, NTOK / 64), 256, 0, stream>>>(h, wv, nullptr, vbuf, NTOK, HKVn * VDn, Dm);
    // 5. RoPE on q and k
    {
        int totq = NTOK * HQn * 32;
        rope_kernel<<<(totq + 255) / 256, 256, 0, stream>>>(q, HQn, totq);
        int totk = NTOK * HKVn * 32;
        rope_kernel<<<(totk + 255) / 256, 256, 0, stream>>>(kbuf, HKVn, totk);
    }
    // 6. attention
    attn_kernel<<<dim3(Tn, HQn, Bn), 256, 0, stream>>>(q, kbuf, vbuf, attnbuf);
    // 7. output projection + residual
    gemm64<1><<<dim3(Dm / 64, NTOK / 64), 256, 0, stream>>>(attnbuf, wo, x, x2, NTOK, Dm, Dm);
    // 8. norm2
    rmsnorm_kernel<<<NTOK, 256, 0, stream>>>(x2, n2s, h2);
    // 9. router
    router_kernel<<<NTOK, 512, 0, stream>>>(h2, router_w, router_b, assign, gate);
    // 10. capacity scan
    scan_kernel<<<1, 256, 0, stream>>>(assign, pos, limit);
    // 11-12. dispatch
    hipMemsetAsync(grouped, 0, (size_t)NE * CAPn * Dm * sizeof(float), stream);
    dispatch_kernel<<<NTOK * 2, 256, 0, stream>>>(h2, assign, pos, grouped);
    // 13. expert FFN stage 1 (fused dual-GEMM + gelu)
    ffn1_gemm<<<dim3(HIDn / 64, CAPn / 64, NE), 256, 0, stream>>>(grouped, w1, w2, hh, limit);
    // 14. expert FFN stage 2
    ffn2_gemm<<<dim3(Dm / 64, CAPn / 64, NE), 256, 0, stream>>>(hh, w3, eout, limit);
    // 15. combine
    combine_kernel<<<NTOK, 256, 0, stream>>>(x2, h2, eout, assign, pos, gate, out);
}

// Round 2
// 1380.336 us; speedup vs baseline: 1.5489x; 1.5489x over previous
//
#include <hip/hip_runtime.h>
#include <math.h>

#define Dm 1024
#define Tn 1024
#define Bn 2
#define NTOK 2048
#define HQn 16
#define HKVn 4
#define KDn 64
#define VDn 64
#define Gn 4
#define NE 8
#define CAPn 1024
#define HIDn 2048

// ---------------- RMSNorm ----------------
__global__ void rmsnorm_kernel(const float* __restrict__ x, const float* __restrict__ scale,
                               float* __restrict__ out) {
    int row = blockIdx.x;
    const float* xr = x + (size_t)row * Dm;
    float ss = 0.f;
    for (int d = threadIdx.x; d < Dm; d += 256) { float v = xr[d]; ss += v * v; }
    __shared__ float red[256];
    red[threadIdx.x] = ss; __syncthreads();
    for (int s = 128; s > 0; s >>= 1) {
        if (threadIdx.x < s) red[threadIdx.x] += red[threadIdx.x + s];
        __syncthreads();
    }
    float inv = rsqrtf(red[0] * (1.f / Dm) + 1e-6f);
    for (int d = threadIdx.x; d < Dm; d += 256)
        out[(size_t)row * Dm + d] = xr[d] * inv * scale[d];
}

// ---------------- Generic fp32 tiled GEMM: C = A@B (+R) ----------------
template<int MODE>  // 0: C=AB   1: C=AB+R
__global__ void gemm64(const float* __restrict__ A, const float* __restrict__ Bm,
                       const float* __restrict__ R, float* __restrict__ C,
                       int M, int N, int K) {
    __shared__ float As[16][68];
    __shared__ float Bs[16][68];
    int tid = threadIdx.x;
    int tx = tid & 15, ty = tid >> 4;
    int arow = blockIdx.y * 64, bcol = blockIdx.x * 64;
    float acc[4][4] = {};
    for (int kk = 0; kk < K; kk += 16) {
        int am = tid >> 2, ak = (tid & 3) * 4;
        float4 a4 = *(const float4*)(A + (size_t)(arow + am) * K + kk + ak);
        As[ak + 0][am] = a4.x; As[ak + 1][am] = a4.y; As[ak + 2][am] = a4.z; As[ak + 3][am] = a4.w;
        int bk = tid >> 4, bn = (tid & 15) * 4;
        *(float4*)&Bs[bk][bn] = *(const float4*)(Bm + (size_t)(kk + bk) * N + bcol + bn);
        __syncthreads();
        #pragma unroll
        for (int k = 0; k < 16; ++k) {
            float4 av = *(float4*)&As[k][ty * 4];
            float4 bv = *(float4*)&Bs[k][tx * 4];
            float a[4] = {av.x, av.y, av.z, av.w};
            float b[4] = {bv.x, bv.y, bv.z, bv.w};
            #pragma unroll
            for (int i = 0; i < 4; ++i)
                #pragma unroll
                for (int j = 0; j < 4; ++j)
                    acc[i][j] += a[i] * b[j];
        }
        __syncthreads();
    }
    #pragma unroll
    for (int i = 0; i < 4; ++i)
        #pragma unroll
        for (int j = 0; j < 4; ++j) {
            int m = arow + ty * 4 + i, n = bcol + tx * 4 + j;
            float v = acc[i][j];
            if (MODE == 1) v += R[(size_t)m * N + n];
            C[(size_t)m * N + n] = v;
        }
}

// ---------------- RoPE (in place) ----------------
__global__ void rope_kernel(float* __restrict__ p, int H, int total) {
    int idx = blockIdx.x * 256 + threadIdx.x;
    if (idx >= total) return;
    int i = idx & 31;
    int h = (idx >> 5) % H;
    int row = idx / (H * 32);
    int t = row & (Tn - 1);
    size_t base = ((size_t)row * H + h) * 64;
    float theta = __expf(-(float)i * (1.f / 32.f) * 9.210340371976184f); // 10000^(-i/32)
    float ang = (float)t * theta;
    float c = cosf(ang), s = sinf(ang);
    float x1 = p[base + i], x2 = p[base + i + 32];
    p[base + i]      = x1 * c - x2 * s;
    p[base + i + 32] = x2 * c + x1 * s;
}

// ---------------- Flash-style tiled attention ----------------
// Grid: (Tn/64, HQn, Bn), block 256. 64 q-rows x 64 s-cols tiles, online softmax.
// LDS: Qs (transposed [k][q]), KP (Ks [k][s], later aliased by Ps [s][q]), Vs [s][dv].
__global__ __launch_bounds__(256) void attn_tile_kernel(const float* __restrict__ q,
                                                        const float* __restrict__ k,
                                                        const float* __restrict__ v,
                                                        float* __restrict__ attn) {
    __shared__ float Qs[64][68];
    __shared__ float KP[64][68];   // Ks phase, then Ps phase (aliased)
    __shared__ float Vs[64][68];
    int tid = threadIdx.x;
    int tx = tid & 15, ty = tid >> 4;
    int tq0 = blockIdx.x * 64;
    int h = blockIdx.y, b = blockIdx.z;
    int kvh = h >> 2;

    // Q tile -> LDS transposed: Qs[d][q_local]
    for (int l = tid; l < 64 * 16; l += 256) {
        int ql = l >> 4, d4 = (l & 15) * 4;
        float4 v4 = *(const float4*)(q + (((size_t)(b * Tn + tq0 + ql)) * HQn + h) * 64 + d4);
        Qs[d4 + 0][ql] = v4.x; Qs[d4 + 1][ql] = v4.y; Qs[d4 + 2][ql] = v4.z; Qs[d4 + 3][ql] = v4.w;
    }

    float m_i[4], l_i[4], O[4][4];
    #pragma unroll
    for (int i = 0; i < 4; ++i) {
        m_i[i] = -1e30f; l_i[i] = 0.f;
        #pragma unroll
        for (int j = 0; j < 4; ++j) O[i][j] = 0.f;
    }

    int nst = (tq0 >> 6) + 1;
    for (int st = 0; st < nst; ++st) {
        int s0 = st * 64;
        __syncthreads();  // prev iter's KP/Vs reads done (also covers Q load, iter 0)
        // K tile -> LDS transposed [d][s]; V tile -> LDS natural [s][d]
        for (int l = tid; l < 64 * 16; l += 256) {
            int sl = l >> 4, d4 = (l & 15) * 4;
            float4 kv = *(const float4*)(k + (((size_t)(b * Tn + s0 + sl)) * HKVn + kvh) * 64 + d4);
            KP[d4 + 0][sl] = kv.x; KP[d4 + 1][sl] = kv.y; KP[d4 + 2][sl] = kv.z; KP[d4 + 3][sl] = kv.w;
            float4 vv = *(const float4*)(v + (((size_t)(b * Tn + s0 + sl)) * HKVn + kvh) * 64 + d4);
            *(float4*)&Vs[sl][d4] = vv;
        }
        __syncthreads();
        // S[q][s] = sum_d Qs[d][q] * Ks[d][s], scaled
        float acc[4][4] = {};
        #pragma unroll 8
        for (int kk = 0; kk < 64; ++kk) {
            float4 av = *(float4*)&Qs[kk][ty * 4];
            float4 bv = *(float4*)&KP[kk][tx * 4];
            float a[4] = {av.x, av.y, av.z, av.w};
            float bb[4] = {bv.x, bv.y, bv.z, bv.w};
            #pragma unroll
            for (int i = 0; i < 4; ++i)
                #pragma unroll
                for (int j = 0; j < 4; ++j)
                    acc[i][j] += a[i] * bb[j];
        }
        bool diag = (s0 == tq0);
        #pragma unroll
        for (int i = 0; i < 4; ++i)
            #pragma unroll
            for (int j = 0; j < 4; ++j) {
                float s_ = acc[i][j] * 0.125f;
                if (diag && (s0 + tx * 4 + j) > (tq0 + ty * 4 + i)) s_ = -1e30f;
                acc[i][j] = s_;
            }
        // row max across the 16 lanes sharing ty
        float mt[4];
        #pragma unroll
        for (int i = 0; i < 4; ++i)
            mt[i] = fmaxf(fmaxf(acc[i][0], acc[i][1]), fmaxf(acc[i][2], acc[i][3]));
        #pragma unroll
        for (int off = 1; off < 16; off <<= 1)
            #pragma unroll
            for (int i = 0; i < 4; ++i) mt[i] = fmaxf(mt[i], __shfl_xor(mt[i], off));
        float rs[4];
        #pragma unroll
        for (int i = 0; i < 4; ++i) {
            float mn = fmaxf(m_i[i], mt[i]);
            float al = __expf(m_i[i] - mn);
            m_i[i] = mn;
            l_i[i] *= al;
            #pragma unroll
            for (int j = 0; j < 4; ++j) O[i][j] *= al;
            rs[i] = 0.f;
            #pragma unroll
            for (int j = 0; j < 4; ++j) {
                float p = __expf(acc[i][j] - mn);
                acc[i][j] = p;
                rs[i] += p;
            }
        }
        #pragma unroll
        for (int off = 1; off < 16; off <<= 1)
            #pragma unroll
            for (int i = 0; i < 4; ++i) rs[i] += __shfl_xor(rs[i], off);
        #pragma unroll
        for (int i = 0; i < 4; ++i) l_i[i] += rs[i];
        __syncthreads();  // all lanes done reading Ks before Ps overwrites it
        // Ps[s][q] = p
        #pragma unroll
        for (int i = 0; i < 4; ++i)
            #pragma unroll
            for (int j = 0; j < 4; ++j)
                KP[tx * 4 + j][ty * 4 + i] = acc[i][j];
        __syncthreads();
        // O[q][dv] += sum_s Ps[s][q] * Vs[s][dv]
        #pragma unroll 8
        for (int ss = 0; ss < 64; ++ss) {
            float4 av = *(float4*)&KP[ss][ty * 4];
            float4 bv = *(float4*)&Vs[ss][tx * 4];
            float a[4] = {av.x, av.y, av.z, av.w};
            float bb[4] = {bv.x, bv.y, bv.z, bv.w};
            #pragma unroll
            for (int i = 0; i < 4; ++i)
                #pragma unroll
                for (int j = 0; j < 4; ++j)
                    O[i][j] += a[i] * bb[j];
        }
    }
    #pragma unroll
    for (int i = 0; i < 4; ++i) {
        float inv = 1.f / l_i[i];
        float4 o4 = make_float4(O[i][0] * inv, O[i][1] * inv, O[i][2] * inv, O[i][3] * inv);
        *(float4*)(attn + ((size_t)(b * Tn + tq0 + ty * 4 + i)) * (HQn * VDn) + h * 64 + tx * 4) = o4;
    }
}

// ---------------- Router: logits + top2 + gates ----------------
__global__ void router_kernel(const float* __restrict__ h2, const float* __restrict__ rw,
                              const float* __restrict__ rb, int* __restrict__ assign,
                              float* __restrict__ gate) {
    int t = blockIdx.x;
    __shared__ float row[Dm];
    __shared__ float logits[NE];
    for (int d = threadIdx.x; d < Dm; d += 512) row[d] = h2[(size_t)t * Dm + d];
    __syncthreads();
    int e = threadIdx.x >> 6, lane = threadIdx.x & 63;
    float part = 0.f;
    for (int d = lane; d < Dm; d += 64) part += row[d] * rw[(size_t)d * NE + e];
    for (int off = 32; off; off >>= 1) part += __shfl_down(part, off);
    if (lane == 0) logits[e] = part + rb[e];
    __syncthreads();
    if (threadIdx.x == 0) {
        int i0 = 0; float m0 = logits[0];
        for (int i = 1; i < NE; ++i) if (logits[i] > m0) { m0 = logits[i]; i0 = i; }
        int i1 = -1; float m1 = -1e30f;
        for (int i = 0; i < NE; ++i) if (i != i0 && logits[i] > m1) { m1 = logits[i]; i1 = i; }
        float e1 = __expf(m1 - m0);
        float s = 1.f + e1;
        assign[t * 2] = i0; assign[t * 2 + 1] = i1;
        gate[t * 2] = 1.f / s; gate[t * 2 + 1] = e1 / s;
    }
}

// ---------------- Capacity scan (single block) ----------------
__global__ void scan_kernel(const int* __restrict__ assign, int* __restrict__ pos,
                            int* __restrict__ limit) {
    __shared__ int cnt[256][16];
    __shared__ int tot[16];
    int tid = threadIdx.x;
    int local[16];
    #pragma unroll
    for (int i = 0; i < 16; ++i) local[i] = 0;
    for (int r = 0; r < 8; ++r) {
        int t = tid * 8 + r;
        local[assign[t * 2]]++;
        local[8 + assign[t * 2 + 1]]++;
    }
    #pragma unroll
    for (int i = 0; i < 16; ++i) cnt[tid][i] = local[i];
    __syncthreads();
    if (tid < 16) {
        int run = 0;
        for (int th = 0; th < 256; ++th) { int v = cnt[th][tid]; cnt[th][tid] = run; run += v; }
        tot[tid] = run;
    }
    __syncthreads();
    int r0[NE], r1[NE];
    #pragma unroll
    for (int e = 0; e < NE; ++e) { r0[e] = cnt[tid][e]; r1[e] = cnt[tid][8 + e]; }
    for (int r = 0; r < 8; ++r) {
        int t = tid * 8 + r;
        int e0 = assign[t * 2], e1 = assign[t * 2 + 1];
        r0[e0]++; pos[t * 2] = r0[e0];
        r1[e1]++; pos[t * 2 + 1] = r0[e1] + r1[e1];
    }
    if (tid == 0)
        for (int e = 0; e < NE; ++e) {
            int C = tot[e] + tot[8 + e];
            limit[e] = C < (CAPn - 1) ? C : (CAPn - 1);
        }
}

// ---------------- Dispatch (scatter-add; collisions sum per reference) ----------------
__global__ void dispatch_kernel(const float* __restrict__ h2, const int* __restrict__ assign,
                                const int* __restrict__ pos, float* __restrict__ grouped) {
    int slot = blockIdx.x; // t*2+j
    int p = pos[slot];
    if (p >= CAPn) return;
    int e = assign[slot];
    const float* src = h2 + (size_t)(slot >> 1) * Dm;
    float* dst = grouped + ((size_t)e * CAPn + p) * Dm;
    for (int d = threadIdx.x; d < Dm; d += 256) atomicAdd(&dst[d], src[d]);
}

__device__ __forceinline__ float gelu_tanh(float y) {
    return 0.5f * y * (1.f + tanhf(0.7978845608028654f * (y + 0.044715f * y * y * y)));
}

// ---------------- Expert FFN stage 1: hh = gelu((A@w2)*(A@w1)) ----------------
__global__ void ffn1_gemm(const float* __restrict__ grouped, const float* __restrict__ w1,
                          const float* __restrict__ w2, float* __restrict__ hh,
                          const int* __restrict__ limit) {
    int e = blockIdx.z;
    if ((int)(blockIdx.y * 64) > limit[e]) return;
    const float* A  = grouped + (size_t)e * CAPn * Dm;
    const float* B1 = w1 + (size_t)e * Dm * HIDn;
    const float* B2 = w2 + (size_t)e * Dm * HIDn;
    float* C = hh + (size_t)e * CAPn * HIDn;
    __shared__ float As[16][68];
    __shared__ float Bs1[16][68];
    __shared__ float Bs2[16][68];
    int tid = threadIdx.x;
    int tx = tid & 15, ty = tid >> 4;
    int arow = blockIdx.y * 64, bcol = blockIdx.x * 64;
    float acc1[4][4] = {}, acc2[4][4] = {};
    for (int kk = 0; kk < Dm; kk += 16) {
        int am = tid >> 2, ak = (tid & 3) * 4;
        float4 a4 = *(const float4*)(A + (size_t)(arow + am) * Dm + kk + ak);
        As[ak + 0][am] = a4.x; As[ak + 1][am] = a4.y; As[ak + 2][am] = a4.z; As[ak + 3][am] = a4.w;
        int bk = tid >> 4, bn = (tid & 15) * 4;
        *(float4*)&Bs1[bk][bn] = *(const float4*)(B1 + (size_t)(kk + bk) * HIDn + bcol + bn);
        *(float4*)&Bs2[bk][bn] = *(const float4*)(B2 + (size_t)(kk + bk) * HIDn + bcol + bn);
        __syncthreads();
        #pragma unroll
        for (int k = 0; k < 16; ++k) {
            float4 av = *(float4*)&As[k][ty * 4];
            float4 b1 = *(float4*)&Bs1[k][tx * 4];
            float4 b2 = *(float4*)&Bs2[k][tx * 4];
            float a[4] = {av.x, av.y, av.z, av.w};
            float v1[4] = {b1.x, b1.y, b1.z, b1.w};
            float v2[4] = {b2.x, b2.y, b2.z, b2.w};
            #pragma unroll
            for (int i = 0; i < 4; ++i)
                #pragma unroll
                for (int j = 0; j < 4; ++j) {
                    acc1[i][j] += a[i] * v1[j];
                    acc2[i][j] += a[i] * v2[j];
                }
        }
        __syncthreads();
    }
    #pragma unroll
    for (int i = 0; i < 4; ++i)
        #pragma unroll
        for (int j = 0; j < 4; ++j) {
            int m = arow + ty * 4 + i, n = bcol + tx * 4 + j;
            C[(size_t)m * HIDn + n] = gelu_tanh(acc2[i][j] * acc1[i][j]);
        }
}

// ---------------- Expert FFN stage 2: eout = hh @ w3 ----------------
__global__ void ffn2_gemm(const float* __restrict__ hh, const float* __restrict__ w3,
                          float* __restrict__ eout, const int* __restrict__ limit) {
    int e = blockIdx.z;
    if ((int)(blockIdx.y * 64) > limit[e]) return;
    const float* A = hh + (size_t)e * CAPn * HIDn;
    const float* Bm = w3 + (size_t)e * HIDn * Dm;
    float* C = eout + (size_t)e * CAPn * Dm;
    __shared__ float As[16][68];
    __shared__ float Bs[16][68];
    int tid = threadIdx.x;
    int tx = tid & 15, ty = tid >> 4;
    int arow = blockIdx.y * 64, bcol = blockIdx.x * 64;
    float acc[4][4] = {};
    for (int kk = 0; kk < HIDn; kk += 16) {
        int am = tid >> 2, ak = (tid & 3) * 4;
        float4 a4 = *(const float4*)(A + (size_t)(arow + am) * HIDn + kk + ak);
        As[ak + 0][am] = a4.x; As[ak + 1][am] = a4.y; As[ak + 2][am] = a4.z; As[ak + 3][am] = a4.w;
        int bk = tid >> 4, bn = (tid & 15) * 4;
        *(float4*)&Bs[bk][bn] = *(const float4*)(Bm + (size_t)(kk + bk) * Dm + bcol + bn);
        __syncthreads();
        #pragma unroll
        for (int k = 0; k < 16; ++k) {
            float4 av = *(float4*)&As[k][ty * 4];
            float4 bv = *(float4*)&Bs[k][tx * 4];
            float a[4] = {av.x, av.y, av.z, av.w};
            float b[4] = {bv.x, bv.y, bv.z, bv.w};
            #pragma unroll
            for (int i = 0; i < 4; ++i)
                #pragma unroll
                for (int j = 0; j < 4; ++j)
                    acc[i][j] += a[i] * b[j];
        }
        __syncthreads();
    }
    #pragma unroll
    for (int i = 0; i < 4; ++i)
        #pragma unroll
        for (int j = 0; j < 4; ++j) {
            int m = arow + ty * 4 + i, n = bcol + tx * 4 + j;
            C[(size_t)m * Dm + n] = acc[i][j];
        }
}

// ---------------- Combine ----------------
__global__ void combine_kernel(const float* __restrict__ x2, const float* __restrict__ h2,
                               const float* __restrict__ eout, const int* __restrict__ assign,
                               const int* __restrict__ pos, const float* __restrict__ gate,
                               float* __restrict__ out) {
    int t = blockIdx.x;
    int e0 = assign[t * 2], e1 = assign[t * 2 + 1];
    int p0 = pos[t * 2],   p1 = pos[t * 2 + 1];
    float g0 = gate[t * 2], g1 = gate[t * 2 + 1];
    const float* src0 = (p0 < CAPn) ? eout + ((size_t)e0 * CAPn + p0) * Dm : h2 + (size_t)t * Dm;
    const float* src1 = (p1 < CAPn) ? eout + ((size_t)e1 * CAPn + p1) * Dm : h2 + (size_t)t * Dm;
    for (int d = threadIdx.x; d < Dm; d += 256)
        out[(size_t)t * Dm + d] = x2[(size_t)t * Dm + d] + g0 * src0[d] + g1 * src1[d];
}

extern "C" void kernel_launch(void* const* d_in, const int* in_sizes, int n_in,
                              void* d_out, int out_size, void* d_ws, size_t ws_size,
                              hipStream_t stream) {
    const float* x        = (const float*)d_in[0];
    const float* wq       = (const float*)d_in[1];
    const float* wk       = (const float*)d_in[2];
    const float* wv       = (const float*)d_in[3];
    const float* wo       = (const float*)d_in[4];
    const float* router_w = (const float*)d_in[5];
    const float* router_b = (const float*)d_in[6];
    const float* w1       = (const float*)d_in[7];
    const float* w2       = (const float*)d_in[8];
    const float* w3       = (const float*)d_in[9];
    const float* n1s      = (const float*)d_in[10];
    const float* n2s      = (const float*)d_in[11];
    float* out = (float*)d_out;
    unsigned char* ws = (unsigned char*)d_ws;
    const size_t MB = 1ull << 20;

    float* h       = (float*)(ws + 0 * MB);
    float* q       = (float*)(ws + 8 * MB);
    float* kbuf    = (float*)(ws + 16 * MB);
    float* vbuf    = (float*)(ws + 18 * MB);
    float* attnbuf = (float*)(ws + 20 * MB);
    float* hh      = (float*)(ws + 0 * MB);
    float* x2      = (float*)(ws + 64 * MB);
    float* h2      = (float*)(ws + 72 * MB);
    int*   assign  = (int*)  (ws + 80 * MB);
    int*   pos     = (int*)  (ws + 80 * MB + 65536);
    float* gate    = (float*)(ws + 80 * MB + 131072);
    int*   limit   = (int*)  (ws + 80 * MB + 196608);
    float* grouped = (float*)(ws + 81 * MB);
    float* eout    = (float*)(ws + 81 * MB);
    (void)in_sizes; (void)n_in; (void)out_size; (void)ws_size;

    rmsnorm_kernel<<<NTOK, 256, 0, stream>>>(x, n1s, h);
    gemm64<0><<<dim3(Dm / 64, NTOK / 64), 256, 0, stream>>>(h, wq, nullptr, q, NTOK, Dm, Dm);
    gemm64<0><<<dim3((HKVn * KDn) / 64, NTOK / 64), 256, 0, stream>>>(h, wk, nullptr, kbuf, NTOK, HKVn * KDn, Dm);
    gemm64<0><<<dim3((HKVn * VDn) / 64, NTOK / 64), 256, 0, stream>>>(h, wv, nullptr, vbuf, NTOK, HKVn * VDn, Dm);
    {
        int totq = NTOK * HQn * 32;
        rope_kernel<<<(totq + 255) / 256, 256, 0, stream>>>(q, HQn, totq);
        int totk = NTOK * HKVn * 32;
        rope_kernel<<<(totk + 255) / 256, 256, 0, stream>>>(kbuf, HKVn, totk);
    }
    attn_tile_kernel<<<dim3(Tn / 64, HQn, Bn), 256, 0, stream>>>(q, kbuf, vbuf, attnbuf);
    gemm64<1><<<dim3(Dm / 64, NTOK / 64), 256, 0, stream>>>(attnbuf, wo, x, x2, NTOK, Dm, Dm);
    rmsnorm_kernel<<<NTOK, 256, 0, stream>>>(x2, n2s, h2);
    router_kernel<<<NTOK, 512, 0, stream>>>(h2, router_w, router_b, assign, gate);
    scan_kernel<<<1, 256, 0, stream>>>(assign, pos, limit);
    hipMemsetAsync(grouped, 0, (size_t)NE * CAPn * Dm * sizeof(float), stream);
    dispatch_kernel<<<NTOK * 2, 256, 0, stream>>>(h2, assign, pos, grouped);
    ffn1_gemm<<<dim3(HIDn / 64, CAPn / 64, NE), 256, 0, stream>>>(grouped, w1, w2, hh, limit);
    ffn2_gemm<<<dim3(Dm / 64, CAPn / 64, NE), 256, 0, stream>>>(hh, w3, eout, limit);
    combine_kernel<<<NTOK, 256, 0, stream>>>(x2, h2, eout, assign, pos, gate, out);
}

// Round 3
// 881.779 us; speedup vs baseline: 2.4247x; 1.5654x over previous
//
#include <hip/hip_runtime.h>
#include <math.h>

#define Dm 1024
#define Tn 1024
#define Bn 2
#define NTOK 2048
#define HQn 16
#define HKVn 4
#define KDn 64
#define VDn 64
#define Gn 4
#define NE 8
#define CAPn 1024
#define HIDn 2048

using frag_ab = __attribute__((ext_vector_type(8))) short;   // 8 bf16
using f32x4  = __attribute__((ext_vector_type(4))) float;

__device__ __forceinline__ unsigned short f2bf(float f) {
    union { float f; unsigned int u; } v; v.f = f;
    unsigned int r = v.u + 0x7FFFu + ((v.u >> 16) & 1u);
    return (unsigned short)(r >> 16);
}
__device__ __forceinline__ float bf2f(unsigned short b) {
    union { unsigned int u; float f; } v; v.u = ((unsigned int)b) << 16;
    return v.f;
}
__device__ __forceinline__ float gelu_fast(float y) {
    float z = 0.7978845608028654f * (y + 0.044715f * y * y * y);
    float az = fabsf(z);
    float t = __expf(-2.f * az);
    float th = (1.f - t) / (1.f + t);
    th = copysignf(th, z);
    return 0.5f * y * (1.f + th);
}

// ---------------- RMSNorm ----------------
__global__ void rmsnorm_kernel(const float* __restrict__ x, const float* __restrict__ scale,
                               float* __restrict__ out) {
    int row = blockIdx.x;
    const float* xr = x + (size_t)row * Dm;
    float ss = 0.f;
    for (int d = threadIdx.x; d < Dm; d += 256) { float v = xr[d]; ss += v * v; }
    __shared__ float red[256];
    red[threadIdx.x] = ss; __syncthreads();
    for (int s = 128; s > 0; s >>= 1) {
        if (threadIdx.x < s) red[threadIdx.x] += red[threadIdx.x + s];
        __syncthreads();
    }
    float inv = rsqrtf(red[0] * (1.f / Dm) + 1e-6f);
    for (int d = threadIdx.x; d < Dm; d += 256)
        out[(size_t)row * Dm + d] = xr[d] * inv * scale[d];
}

// ---------------- Generic fp32 tiled GEMM: C = A@B (+R) ----------------
template<int MODE>  // 0: C=AB   1: C=AB+R
__global__ void gemm64(const float* __restrict__ A, const float* __restrict__ Bm,
                       const float* __restrict__ R, float* __restrict__ C,
                       int M, int N, int K) {
    __shared__ float As[16][68];
    __shared__ float Bs[16][68];
    int tid = threadIdx.x;
    int tx = tid & 15, ty = tid >> 4;
    int arow = blockIdx.y * 64, bcol = blockIdx.x * 64;
    float acc[4][4] = {};
    for (int kk = 0; kk < K; kk += 16) {
        int am = tid >> 2, ak = (tid & 3) * 4;
        float4 a4 = *(const float4*)(A + (size_t)(arow + am) * K + kk + ak);
        As[ak + 0][am] = a4.x; As[ak + 1][am] = a4.y; As[ak + 2][am] = a4.z; As[ak + 3][am] = a4.w;
        int bk = tid >> 4, bn = (tid & 15) * 4;
        *(float4*)&Bs[bk][bn] = *(const float4*)(Bm + (size_t)(kk + bk) * N + bcol + bn);
        __syncthreads();
        #pragma unroll
        for (int k = 0; k < 16; ++k) {
            float4 av = *(float4*)&As[k][ty * 4];
            float4 bv = *(float4*)&Bs[k][tx * 4];
            float a[4] = {av.x, av.y, av.z, av.w};
            float b[4] = {bv.x, bv.y, bv.z, bv.w};
            #pragma unroll
            for (int i = 0; i < 4; ++i)
                #pragma unroll
                for (int j = 0; j < 4; ++j)
                    acc[i][j] += a[i] * b[j];
        }
        __syncthreads();
    }
    #pragma unroll
    for (int i = 0; i < 4; ++i)
        #pragma unroll
        for (int j = 0; j < 4; ++j) {
            int m = arow + ty * 4 + i, n = bcol + tx * 4 + j;
            float v = acc[i][j];
            if (MODE == 1) v += R[(size_t)m * N + n];
            C[(size_t)m * N + n] = v;
        }
}

// ---------------- RoPE (in place) ----------------
__global__ void rope_kernel(float* __restrict__ p, int H, int total) {
    int idx = blockIdx.x * 256 + threadIdx.x;
    if (idx >= total) return;
    int i = idx & 31;
    int h = (idx >> 5) % H;
    int row = idx / (H * 32);
    int t = row & (Tn - 1);
    size_t base = ((size_t)row * H + h) * 64;
    float theta = __expf(-(float)i * (1.f / 32.f) * 9.210340371976184f); // 10000^(-i/32)
    float ang = (float)t * theta;
    float c = cosf(ang), s = sinf(ang);
    float x1 = p[base + i], x2 = p[base + i + 32];
    p[base + i]      = x1 * c - x2 * s;
    p[base + i + 32] = x2 * c + x1 * s;
}

// ---------------- Flash-style tiled attention ----------------
__global__ __launch_bounds__(256) void attn_tile_kernel(const float* __restrict__ q,
                                                        const float* __restrict__ k,
                                                        const float* __restrict__ v,
                                                        float* __restrict__ attn) {
    __shared__ float Qs[64][68];
    __shared__ float KP[64][68];   // Ks phase, then Ps phase (aliased)
    __shared__ float Vs[64][68];
    int tid = threadIdx.x;
    int tx = tid & 15, ty = tid >> 4;
    int tq0 = blockIdx.x * 64;
    int h = blockIdx.y, b = blockIdx.z;
    int kvh = h >> 2;

    for (int l = tid; l < 64 * 16; l += 256) {
        int ql = l >> 4, d4 = (l & 15) * 4;
        float4 v4 = *(const float4*)(q + (((size_t)(b * Tn + tq0 + ql)) * HQn + h) * 64 + d4);
        Qs[d4 + 0][ql] = v4.x; Qs[d4 + 1][ql] = v4.y; Qs[d4 + 2][ql] = v4.z; Qs[d4 + 3][ql] = v4.w;
    }

    float m_i[4], l_i[4], O[4][4];
    #pragma unroll
    for (int i = 0; i < 4; ++i) {
        m_i[i] = -1e30f; l_i[i] = 0.f;
        #pragma unroll
        for (int j = 0; j < 4; ++j) O[i][j] = 0.f;
    }

    int nst = (tq0 >> 6) + 1;
    for (int st = 0; st < nst; ++st) {
        int s0 = st * 64;
        __syncthreads();
        for (int l = tid; l < 64 * 16; l += 256) {
            int sl = l >> 4, d4 = (l & 15) * 4;
            float4 kv = *(const float4*)(k + (((size_t)(b * Tn + s0 + sl)) * HKVn + kvh) * 64 + d4);
            KP[d4 + 0][sl] = kv.x; KP[d4 + 1][sl] = kv.y; KP[d4 + 2][sl] = kv.z; KP[d4 + 3][sl] = kv.w;
            float4 vv = *(const float4*)(v + (((size_t)(b * Tn + s0 + sl)) * HKVn + kvh) * 64 + d4);
            *(float4*)&Vs[sl][d4] = vv;
        }
        __syncthreads();
        float acc[4][4] = {};
        #pragma unroll 8
        for (int kk = 0; kk < 64; ++kk) {
            float4 av = *(float4*)&Qs[kk][ty * 4];
            float4 bv = *(float4*)&KP[kk][tx * 4];
            float a[4] = {av.x, av.y, av.z, av.w};
            float bb[4] = {bv.x, bv.y, bv.z, bv.w};
            #pragma unroll
            for (int i = 0; i < 4; ++i)
                #pragma unroll
                for (int j = 0; j < 4; ++j)
                    acc[i][j] += a[i] * bb[j];
        }
        bool diag = (s0 == tq0);
        #pragma unroll
        for (int i = 0; i < 4; ++i)
            #pragma unroll
            for (int j = 0; j < 4; ++j) {
                float s_ = acc[i][j] * 0.125f;
                if (diag && (s0 + tx * 4 + j) > (tq0 + ty * 4 + i)) s_ = -1e30f;
                acc[i][j] = s_;
            }
        float mt[4];
        #pragma unroll
        for (int i = 0; i < 4; ++i)
            mt[i] = fmaxf(fmaxf(acc[i][0], acc[i][1]), fmaxf(acc[i][2], acc[i][3]));
        #pragma unroll
        for (int off = 1; off < 16; off <<= 1)
            #pragma unroll
            for (int i = 0; i < 4; ++i) mt[i] = fmaxf(mt[i], __shfl_xor(mt[i], off));
        float rs[4];
        #pragma unroll
        for (int i = 0; i < 4; ++i) {
            float mn = fmaxf(m_i[i], mt[i]);
            float al = __expf(m_i[i] - mn);
            m_i[i] = mn;
            l_i[i] *= al;
            #pragma unroll
            for (int j = 0; j < 4; ++j) O[i][j] *= al;
            rs[i] = 0.f;
            #pragma unroll
            for (int j = 0; j < 4; ++j) {
                float p = __expf(acc[i][j] - mn);
                acc[i][j] = p;
                rs[i] += p;
            }
        }
        #pragma unroll
        for (int off = 1; off < 16; off <<= 1)
            #pragma unroll
            for (int i = 0; i < 4; ++i) rs[i] += __shfl_xor(rs[i], off);
        #pragma unroll
        for (int i = 0; i < 4; ++i) l_i[i] += rs[i];
        __syncthreads();
        #pragma unroll
        for (int i = 0; i < 4; ++i)
            #pragma unroll
            for (int j = 0; j < 4; ++j)
                KP[tx * 4 + j][ty * 4 + i] = acc[i][j];
        __syncthreads();
        #pragma unroll 8
        for (int ss = 0; ss < 64; ++ss) {
            float4 av = *(float4*)&KP[ss][ty * 4];
            float4 bv = *(float4*)&Vs[ss][tx * 4];
            float a[4] = {av.x, av.y, av.z, av.w};
            float bb[4] = {bv.x, bv.y, bv.z, bv.w};
            #pragma unroll
            for (int i = 0; i < 4; ++i)
                #pragma unroll
                for (int j = 0; j < 4; ++j)
                    O[i][j] += a[i] * bb[j];
        }
    }
    #pragma unroll
    for (int i = 0; i < 4; ++i) {
        float inv = 1.f / l_i[i];
        float4 o4 = make_float4(O[i][0] * inv, O[i][1] * inv, O[i][2] * inv, O[i][3] * inv);
        *(float4*)(attn + ((size_t)(b * Tn + tq0 + ty * 4 + i)) * (HQn * VDn) + h * 64 + tx * 4) = o4;
    }
}

// ---------------- Router ----------------
__global__ void router_kernel(const float* __restrict__ h2, const float* __restrict__ rw,
                              const float* __restrict__ rb, int* __restrict__ assign,
                              float* __restrict__ gate) {
    int t = blockIdx.x;
    __shared__ float row[Dm];
    __shared__ float logits[NE];
    for (int d = threadIdx.x; d < Dm; d += 512) row[d] = h2[(size_t)t * Dm + d];
    __syncthreads();
    int e = threadIdx.x >> 6, lane = threadIdx.x & 63;
    float part = 0.f;
    for (int d = lane; d < Dm; d += 64) part += row[d] * rw[(size_t)d * NE + e];
    for (int off = 32; off; off >>= 1) part += __shfl_down(part, off);
    if (lane == 0) logits[e] = part + rb[e];
    __syncthreads();
    if (threadIdx.x == 0) {
        int i0 = 0; float m0 = logits[0];
        for (int i = 1; i < NE; ++i) if (logits[i] > m0) { m0 = logits[i]; i0 = i; }
        int i1 = -1; float m1 = -1e30f;
        for (int i = 0; i < NE; ++i) if (i != i0 && logits[i] > m1) { m1 = logits[i]; i1 = i; }
        float e1 = __expf(m1 - m0);
        float s = 1.f + e1;
        assign[t * 2] = i0; assign[t * 2 + 1] = i1;
        gate[t * 2] = 1.f / s; gate[t * 2 + 1] = e1 / s;
    }
}

// ---------------- Capacity scan (single block) ----------------
__global__ void scan_kernel(const int* __restrict__ assign, int* __restrict__ pos,
                            int* __restrict__ limit) {
    __shared__ int cnt[256][16];
    __shared__ int tot[16];
    int tid = threadIdx.x;
    int local[16];
    #pragma unroll
    for (int i = 0; i < 16; ++i) local[i] = 0;
    for (int r = 0; r < 8; ++r) {
        int t = tid * 8 + r;
        local[assign[t * 2]]++;
        local[8 + assign[t * 2 + 1]]++;
    }
    #pragma unroll
    for (int i = 0; i < 16; ++i) cnt[tid][i] = local[i];
    __syncthreads();
    if (tid < 16) {
        int run = 0;
        for (int th = 0; th < 256; ++th) { int v = cnt[th][tid]; cnt[th][tid] = run; run += v; }
        tot[tid] = run;
    }
    __syncthreads();
    int r0[NE], r1[NE];
    #pragma unroll
    for (int e = 0; e < NE; ++e) { r0[e] = cnt[tid][e]; r1[e] = cnt[tid][8 + e]; }
    for (int r = 0; r < 8; ++r) {
        int t = tid * 8 + r;
        int e0 = assign[t * 2], e1 = assign[t * 2 + 1];
        r0[e0]++; pos[t * 2] = r0[e0];
        r1[e1]++; pos[t * 2 + 1] = r0[e1] + r1[e1];
    }
    if (tid == 0)
        for (int e = 0; e < NE; ++e) {
            int C = tot[e] + tot[8 + e];
            limit[e] = C < (CAPn - 1) ? C : (CAPn - 1);
        }
}

// ---------------- Dispatch (fp32 scatter-add; collisions sum per reference) ----------------
__global__ void dispatch_kernel(const float* __restrict__ h2, const int* __restrict__ assign,
                                const int* __restrict__ pos, float* __restrict__ grouped) {
    int slot = blockIdx.x;
    int p = pos[slot];
    if (p >= CAPn) return;
    int e = assign[slot];
    const float* src = h2 + (size_t)(slot >> 1) * Dm;
    float* dst = grouped + ((size_t)e * CAPn + p) * Dm;
    for (int d = threadIdx.x; d < Dm; d += 256) atomicAdd(&dst[d], src[d]);
}

// ---------------- fp32 -> bf16 elementwise convert (vector) ----------------
__global__ void convert_bf16(const float* __restrict__ in, unsigned short* __restrict__ out, int n4) {
    int i = blockIdx.x * 256 + threadIdx.x;
    if (i >= n4) return;
    float4 v = ((const float4*)in)[i];
    unsigned long long pk = (unsigned long long)f2bf(v.x)
                          | ((unsigned long long)f2bf(v.y) << 16)
                          | ((unsigned long long)f2bf(v.z) << 32)
                          | ((unsigned long long)f2bf(v.w) << 48);
    ((unsigned long long*)out)[i] = pk;
}

// ---------------- fp32 [R][C] -> bf16 [C][R] transpose+convert, per expert ----------------
__global__ void transpose_convert(const float* __restrict__ in, unsigned short* __restrict__ out,
                                  int R, int Ccols) {
    int e = blockIdx.z;
    in  += (size_t)e * R * Ccols;
    out += (size_t)e * R * Ccols;
    __shared__ float T[64][65];
    int tid = threadIdx.x;
    int r0 = blockIdx.y * 64, c0 = blockIdx.x * 64;
    #pragma unroll
    for (int rep = 0; rep < 4; ++rep) {
        int r = (tid >> 4) + rep * 16;
        int c = (tid & 15) * 4;
        float4 v = *(const float4*)(in + (size_t)(r0 + r) * Ccols + c0 + c);
        T[r][c] = v.x; T[r][c + 1] = v.y; T[r][c + 2] = v.z; T[r][c + 3] = v.w;
    }
    __syncthreads();
    #pragma unroll
    for (int rep = 0; rep < 4; ++rep) {
        int c = rep * 16 + (tid >> 4);
        int r = (tid & 15) * 4;
        unsigned long long pk = (unsigned long long)f2bf(T[r][c])
                              | ((unsigned long long)f2bf(T[r + 1][c]) << 16)
                              | ((unsigned long long)f2bf(T[r + 2][c]) << 32)
                              | ((unsigned long long)f2bf(T[r + 3][c]) << 48);
        *(unsigned long long*)(out + (size_t)(c0 + c) * R + r0 + r) = pk;
    }
}

// ---------------- bf16 MFMA GEMM: C[m][n] (+epilogue) = A[m][k] @ Bt[n][k]^T ----------------
// 128x128 tile / block, 256 thr = 4 waves (2x2), each wave 64x64 via 4x4 16x16x32 MFMAs.
// GELU mode: C := gelu(acc * bf2f(C)) in-place combine (for gated FFN).
template<bool GELU>
__global__ __launch_bounds__(256) void mfma_gemm(const unsigned short* __restrict__ A,
                                                 const unsigned short* __restrict__ Bt,
                                                 unsigned short* __restrict__ C,
                                                 int N, int K, const int* __restrict__ limit) {
    int e = blockIdx.z;
    int m0 = blockIdx.y * 128;
    if (m0 > limit[e]) return;
    A  += (size_t)e * CAPn * K;
    Bt += (size_t)e * N * K;
    C  += (size_t)e * CAPn * N;
    int n0 = blockIdx.x * 128;
    __shared__ unsigned short As[128 * 32];   // [m][k], 64B rows
    __shared__ unsigned short Bs[128 * 32];   // [n][k], 64B rows
    int tid = threadIdx.x, wave = tid >> 6, lane = tid & 63;
    int quad = lane >> 4, r16 = lane & 15;
    int wm = wave & 1, wn = wave >> 1;
    f32x4 acc[4][4];
    #pragma unroll
    for (int mt = 0; mt < 4; ++mt)
        #pragma unroll
        for (int nt = 0; nt < 4; ++nt) {
            acc[mt][nt][0] = 0.f; acc[mt][nt][1] = 0.f;
            acc[mt][nt][2] = 0.f; acc[mt][nt][3] = 0.f;
        }
    const size_t rs = (size_t)K * 2;  // row stride bytes (both A and Bt)
    const char* ga0 = (const char*)A  + (size_t)m0 * rs;
    const char* gb0 = (const char*)Bt + (size_t)n0 * rs;
    for (int kk = 0; kk < K; kk += 32) {
        __syncthreads();
        #pragma unroll
        for (int i = 0; i < 2; ++i) {
            int r = wave * 16 + i * 64 + (lane >> 2);
            size_t go = (size_t)r * rs + (size_t)kk * 2 + (lane & 3) * 16;
            int lofs = wave * 1024 + i * 4096;
            __builtin_amdgcn_global_load_lds(
                (const __attribute__((address_space(1))) void*)(ga0 + go),
                (__attribute__((address_space(3))) void*)((char*)As + lofs), 16, 0, 0);
            __builtin_amdgcn_global_load_lds(
                (const __attribute__((address_space(1))) void*)(gb0 + go),
                (__attribute__((address_space(3))) void*)((char*)Bs + lofs), 16, 0, 0);
        }
        __syncthreads();
        frag_ab a[4], b[4];
        #pragma unroll
        for (int t = 0; t < 4; ++t) {
            a[t] = *(const frag_ab*)((const char*)As + (wm * 64 + t * 16 + r16) * 64 + quad * 16);
            b[t] = *(const frag_ab*)((const char*)Bs + (wn * 64 + t * 16 + r16) * 64 + quad * 16);
        }
        #pragma unroll
        for (int mt = 0; mt < 4; ++mt)
            #pragma unroll
            for (int nt = 0; nt < 4; ++nt)
                acc[mt][nt] = __builtin_amdgcn_mfma_f32_16x16x32_bf16(a[mt], b[nt], acc[mt][nt], 0, 0, 0);
    }
    #pragma unroll
    for (int mt = 0; mt < 4; ++mt)
        #pragma unroll
        for (int nt = 0; nt < 4; ++nt)
            #pragma unroll
            for (int r = 0; r < 4; ++r) {
                int m = m0 + wm * 64 + mt * 16 + quad * 4 + r;
                int n = n0 + wn * 64 + nt * 16 + r16;
                size_t idx = (size_t)m * N + n;
                float v = acc[mt][nt][r];
                if (GELU) v = gelu_fast(v * bf2f(C[idx]));
                C[idx] = f2bf(v);
            }
}

// ---------------- Combine (eout is bf16) ----------------
__global__ void combine_kernel(const float* __restrict__ x2, const float* __restrict__ h2,
                               const unsigned short* __restrict__ eout, const int* __restrict__ assign,
                               const int* __restrict__ pos, const float* __restrict__ gate,
                               float* __restrict__ out) {
    int t = blockIdx.x;
    int e0 = assign[t * 2], e1 = assign[t * 2 + 1];
    int p0 = pos[t * 2],   p1 = pos[t * 2 + 1];
    float g0 = gate[t * 2], g1 = gate[t * 2 + 1];
    bool k0 = p0 < CAPn, k1 = p1 < CAPn;
    const unsigned short* s0 = eout + ((size_t)e0 * CAPn + p0) * Dm;
    const unsigned short* s1 = eout + ((size_t)e1 * CAPn + p1) * Dm;
    const float* hb = h2 + (size_t)t * Dm;
    for (int d = threadIdx.x; d < Dm; d += 256) {
        float v0 = k0 ? bf2f(s0[d]) : hb[d];
        float v1 = k1 ? bf2f(s1[d]) : hb[d];
        out[(size_t)t * Dm + d] = x2[(size_t)t * Dm + d] + g0 * v0 + g1 * v1;
    }
}

extern "C" void kernel_launch(void* const* d_in, const int* in_sizes, int n_in,
                              void* d_out, int out_size, void* d_ws, size_t ws_size,
                              hipStream_t stream) {
    const float* x        = (const float*)d_in[0];
    const float* wq       = (const float*)d_in[1];
    const float* wk       = (const float*)d_in[2];
    const float* wv       = (const float*)d_in[3];
    const float* wo       = (const float*)d_in[4];
    const float* router_w = (const float*)d_in[5];
    const float* router_b = (const float*)d_in[6];
    const float* w1       = (const float*)d_in[7];
    const float* w2       = (const float*)d_in[8];
    const float* w3       = (const float*)d_in[9];
    const float* n1s      = (const float*)d_in[10];
    const float* n2s      = (const float*)d_in[11];
    float* out = (float*)d_out;
    unsigned char* ws = (unsigned char*)d_ws;
    const size_t MB = 1ull << 20;

    // Workspace (peak 113 MB, timeline-aliased):
    //  attn phase:  h[0,8) q[8,16) k[16,18) v[18,20) attn[20,28)
    //  MoE phase:   grouped_f32[0,32) -> tmp1/hh bf16 [0,32) (in-place gated FFN)
    //  persistent:  x2[32,40) h2[40,48) small[48,48.25) grouped_bf16[49,65)
    //               wtslot[65,97) (w1t -> w2t -> w3t)  eout_bf16[97,113)
    float* h       = (float*)(ws + 0 * MB);
    float* q       = (float*)(ws + 8 * MB);
    float* kbuf    = (float*)(ws + 16 * MB);
    float* vbuf    = (float*)(ws + 18 * MB);
    float* attnbuf = (float*)(ws + 20 * MB);
    float* grouped_f32   = (float*)(ws + 0 * MB);
    unsigned short* tmp1hh = (unsigned short*)(ws + 0 * MB);
    float* x2      = (float*)(ws + 32 * MB);
    float* h2      = (float*)(ws + 40 * MB);
    int*   assign  = (int*)  (ws + 48 * MB);
    int*   pos     = (int*)  (ws + 48 * MB + 65536);
    float* gate    = (float*)(ws + 48 * MB + 131072);
    int*   limit   = (int*)  (ws + 48 * MB + 196608);
    unsigned short* grouped_bf = (unsigned short*)(ws + 49 * MB);
    unsigned short* wtslot     = (unsigned short*)(ws + 65 * MB);
    unsigned short* eout       = (unsigned short*)(ws + 97 * MB);
    (void)in_sizes; (void)n_in; (void)out_size; (void)ws_size;

    // ---- attention half ----
    rmsnorm_kernel<<<NTOK, 256, 0, stream>>>(x, n1s, h);
    gemm64<0><<<dim3(Dm / 64, NTOK / 64), 256, 0, stream>>>(h, wq, nullptr, q, NTOK, Dm, Dm);
    gemm64<0><<<dim3((HKVn * KDn) / 64, NTOK / 64), 256, 0, stream>>>(h, wk, nullptr, kbuf, NTOK, HKVn * KDn, Dm);
    gemm64<0><<<dim3((HKVn * VDn) / 64, NTOK / 64), 256, 0, stream>>>(h, wv, nullptr, vbuf, NTOK, HKVn * VDn, Dm);
    {
        int totq = NTOK * HQn * 32;
        rope_kernel<<<(totq + 255) / 256, 256, 0, stream>>>(q, HQn, totq);
        int totk = NTOK * HKVn * 32;
        rope_kernel<<<(totk + 255) / 256, 256, 0, stream>>>(kbuf, HKVn, totk);
    }
    attn_tile_kernel<<<dim3(Tn / 64, HQn, Bn), 256, 0, stream>>>(q, kbuf, vbuf, attnbuf);
    gemm64<1><<<dim3(Dm / 64, NTOK / 64), 256, 0, stream>>>(attnbuf, wo, x, x2, NTOK, Dm, Dm);
    // ---- MoE half ----
    rmsnorm_kernel<<<NTOK, 256, 0, stream>>>(x2, n2s, h2);
    router_kernel<<<NTOK, 512, 0, stream>>>(h2, router_w, router_b, assign, gate);
    scan_kernel<<<1, 256, 0, stream>>>(assign, pos, limit);
    hipMemsetAsync(grouped_f32, 0, (size_t)NE * CAPn * Dm * sizeof(float), stream);
    dispatch_kernel<<<NTOK * 2, 256, 0, stream>>>(h2, assign, pos, grouped_f32);
    convert_bf16<<<(NE * CAPn * Dm / 4 + 255) / 256, 256, 0, stream>>>(grouped_f32, grouped_bf, NE * CAPn * Dm / 4);
    // tmp1 = grouped @ w1   (bf16, into tmp1hh)
    transpose_convert<<<dim3(HIDn / 64, Dm / 64, NE), 256, 0, stream>>>(w1, wtslot, Dm, HIDn);
    mfma_gemm<false><<<dim3(HIDn / 128, CAPn / 128, NE), 256, 0, stream>>>(grouped_bf, wtslot, tmp1hh, HIDn, Dm, limit);
    // hh = gelu((grouped @ w2) * tmp1)   (in-place on tmp1hh)
    transpose_convert<<<dim3(HIDn / 64, Dm / 64, NE), 256, 0, stream>>>(w2, wtslot, Dm, HIDn);
    mfma_gemm<true><<<dim3(HIDn / 128, CAPn / 128, NE), 256, 0, stream>>>(grouped_bf, wtslot, tmp1hh, HIDn, Dm, limit);
    // eout = hh @ w3
    transpose_convert<<<dim3(Dm / 64, HIDn / 64, NE), 256, 0, stream>>>(w3, wtslot, HIDn, Dm);
    mfma_gemm<false><<<dim3(Dm / 128, CAPn / 128, NE), 256, 0, stream>>>(tmp1hh, wtslot, eout, Dm, HIDn, limit);
    // combine
    combine_kernel<<<NTOK, 256, 0, stream>>>(x2, h2, eout, assign, pos, gate, out);
}

// Round 4
// 569.717 us; speedup vs baseline: 3.7528x; 1.5477x over previous
//
#include <hip/hip_runtime.h>
#include <math.h>

#define Dm 1024
#define Tn 1024
#define Bn 2
#define NTOK 2048
#define HQn 16
#define HKVn 4
#define KDn 64
#define VDn 64
#define Gn 4
#define NE 8
#define CAPn 1024
#define HIDn 2048
#define QKVS 1536   // qkv row stride (elems): q[0,1024) k[1024,1280) v[1280,1536)

using frag_ab = __attribute__((ext_vector_type(8))) short;   // 8 bf16
using f32x4  = __attribute__((ext_vector_type(4))) float;

__device__ __forceinline__ unsigned short f2bf(float f) {
    union { float f; unsigned int u; } v; v.f = f;
    unsigned int r = v.u + 0x7FFFu + ((v.u >> 16) & 1u);
    return (unsigned short)(r >> 16);
}
__device__ __forceinline__ float bf2f(unsigned short b) {
    union { unsigned int u; float f; } v; v.u = ((unsigned int)b) << 16;
    return v.f;
}
__device__ __forceinline__ float gelu_fast(float y) {
    float z = 0.7978845608028654f * (y + 0.044715f * y * y * y);
    float az = fabsf(z);
    float t = __expf(-2.f * az);
    float th = (1.f - t) / (1.f + t);
    th = copysignf(th, z);
    return 0.5f * y * (1.f + th);
}

// ---------------- RMSNorm (templated output dtype) ----------------
template<int BF>  // 0: fp32 out, 1: bf16 out
__global__ void rmsnorm_kernel(const float* __restrict__ x, const float* __restrict__ scale,
                               void* __restrict__ outv) {
    int row = blockIdx.x;
    const float* xr = x + (size_t)row * Dm;
    float ss = 0.f;
    for (int d = threadIdx.x; d < Dm; d += 256) { float v = xr[d]; ss += v * v; }
    __shared__ float red[256];
    red[threadIdx.x] = ss; __syncthreads();
    for (int s = 128; s > 0; s >>= 1) {
        if (threadIdx.x < s) red[threadIdx.x] += red[threadIdx.x + s];
        __syncthreads();
    }
    float inv = rsqrtf(red[0] * (1.f / Dm) + 1e-6f);
    for (int d = threadIdx.x; d < Dm; d += 256) {
        float v = xr[d] * inv * scale[d];
        if (BF) ((unsigned short*)outv)[(size_t)row * Dm + d] = f2bf(v);
        else    ((float*)outv)[(size_t)row * Dm + d] = v;
    }
}

// ---------------- fp32 [R][C] -> bf16 [C][R] transpose+convert (z = expert or 1) ----------------
__global__ void transpose_convert(const float* __restrict__ in, unsigned short* __restrict__ out,
                                  int R, int Ccols) {
    int e = blockIdx.z;
    in  += (size_t)e * R * Ccols;
    out += (size_t)e * R * Ccols;
    __shared__ float T[64][65];
    int tid = threadIdx.x;
    int r0 = blockIdx.y * 64, c0 = blockIdx.x * 64;
    #pragma unroll
    for (int rep = 0; rep < 4; ++rep) {
        int r = (tid >> 4) + rep * 16;
        int c = (tid & 15) * 4;
        float4 v = *(const float4*)(in + (size_t)(r0 + r) * Ccols + c0 + c);
        T[r][c] = v.x; T[r][c + 1] = v.y; T[r][c + 2] = v.z; T[r][c + 3] = v.w;
    }
    __syncthreads();
    #pragma unroll
    for (int rep = 0; rep < 4; ++rep) {
        int c = rep * 16 + (tid >> 4);
        int r = (tid & 15) * 4;
        unsigned long long pk = (unsigned long long)f2bf(T[r][c])
                              | ((unsigned long long)f2bf(T[r + 1][c]) << 16)
                              | ((unsigned long long)f2bf(T[r + 2][c]) << 32)
                              | ((unsigned long long)f2bf(T[r + 3][c]) << 48);
        *(unsigned long long*)(out + (size_t)(c0 + c) * R + r0 + r) = pk;
    }
}

// ---------------- generic bf16 MFMA GEMM: C[m][n] = A[m][k] @ Bt[n][k]^T ----------------
// MODE 0: bf16 C.  MODE 1: fp32 C = acc + R (residual).
template<int MODE>
__global__ __launch_bounds__(256) void mfma_gemm2(const unsigned short* __restrict__ A,
                                                  const unsigned short* __restrict__ Bt,
                                                  void* __restrict__ Cout,
                                                  const float* __restrict__ R,
                                                  int N, int K) {
    int m0 = blockIdx.y * 128, n0 = blockIdx.x * 128;
    __shared__ unsigned short As[128 * 32];
    __shared__ unsigned short Bs[128 * 32];
    int tid = threadIdx.x, wave = tid >> 6, lane = tid & 63;
    int quad = lane >> 4, r16 = lane & 15;
    int wm = wave & 1, wn = wave >> 1;
    f32x4 acc[4][4];
    #pragma unroll
    for (int mt = 0; mt < 4; ++mt)
        #pragma unroll
        for (int nt = 0; nt < 4; ++nt) acc[mt][nt] = (f32x4){0.f, 0.f, 0.f, 0.f};
    const size_t rs = (size_t)K * 2;
    const char* ga0 = (const char*)A  + (size_t)m0 * rs;
    const char* gb0 = (const char*)Bt + (size_t)n0 * rs;
    for (int kk = 0; kk < K; kk += 32) {
        __syncthreads();
        #pragma unroll
        for (int i = 0; i < 2; ++i) {
            int r = wave * 16 + i * 64 + (lane >> 2);
            size_t go = (size_t)r * rs + (size_t)kk * 2 + (lane & 3) * 16;
            int lofs = wave * 1024 + i * 4096;
            __builtin_amdgcn_global_load_lds(
                (const __attribute__((address_space(1))) void*)(ga0 + go),
                (__attribute__((address_space(3))) void*)((char*)As + lofs), 16, 0, 0);
            __builtin_amdgcn_global_load_lds(
                (const __attribute__((address_space(1))) void*)(gb0 + go),
                (__attribute__((address_space(3))) void*)((char*)Bs + lofs), 16, 0, 0);
        }
        __syncthreads();
        frag_ab a[4], b[4];
        #pragma unroll
        for (int t = 0; t < 4; ++t) {
            a[t] = *(const frag_ab*)((const char*)As + (wm * 64 + t * 16 + r16) * 64 + quad * 16);
            b[t] = *(const frag_ab*)((const char*)Bs + (wn * 64 + t * 16 + r16) * 64 + quad * 16);
        }
        #pragma unroll
        for (int mt = 0; mt < 4; ++mt)
            #pragma unroll
            for (int nt = 0; nt < 4; ++nt)
                acc[mt][nt] = __builtin_amdgcn_mfma_f32_16x16x32_bf16(a[mt], b[nt], acc[mt][nt], 0, 0, 0);
    }
    #pragma unroll
    for (int mt = 0; mt < 4; ++mt)
        #pragma unroll
        for (int nt = 0; nt < 4; ++nt)
            #pragma unroll
            for (int r = 0; r < 4; ++r) {
                int m = m0 + wm * 64 + mt * 16 + quad * 4 + r;
                int n = n0 + wn * 64 + nt * 16 + r16;
                size_t idx = (size_t)m * N + n;
                float v = acc[mt][nt][r];
                if (MODE == 0) ((unsigned short*)Cout)[idx] = f2bf(v);
                else           ((float*)Cout)[idx] = v + R[idx];
            }
}

// ---------------- RoPE on bf16 qkv (in place); q pre-scaled by 0.125*log2e ----------------
__global__ void rope_bf16(unsigned short* __restrict__ p) {
    int idx = blockIdx.x * 256 + threadIdx.x;
    const int QC = NTOK * HQn * 32;
    int i, col, row; float scale;
    if (idx < QC) {
        i = idx & 31; int h = (idx >> 5) & 15; row = idx >> 9;
        col = h * 64 + i; scale = 0.18033688011112042f;  // 0.125 * log2(e)
    } else {
        int r = idx - QC;
        i = r & 31; int h = (r >> 5) & 3; row = r >> 7;
        col = 1024 + h * 64 + i; scale = 1.f;
    }
    int t = row & (Tn - 1);
    size_t base = (size_t)row * QKVS + col;
    float theta = __expf(-(float)i * (1.f / 32.f) * 9.210340371976184f); // 10000^(-i/32)
    float ang = (float)t * theta;
    float c = cosf(ang), s = sinf(ang);
    float x1 = bf2f(p[base]), x2 = bf2f(p[base + 32]);
    p[base]      = f2bf((x1 * c - x2 * s) * scale);
    p[base + 32] = f2bf((x2 * c + x1 * s) * scale);
}

// ---------------- MFMA flash attention ----------------
// grid (Tn/128, HQn, Bn), 256 thr = 4 waves x 32 q-rows. S-steps of 128 cols.
// LDS (shorts): Ps[128][128] sw16 | Ks[128][64] sw8 | Vt[64][128] sw16 (Q staged here first)
__global__ __launch_bounds__(256) void mfma_attn(const unsigned short* __restrict__ qkv,
                                                 unsigned short* __restrict__ attnb) {
    __shared__ unsigned short lds[32768];
    unsigned short* Ps = lds;
    unsigned short* Ks = lds + 16384;
    unsigned short* Vt = lds + 24576;
    int tid = threadIdx.x, wave = tid >> 6, lane = tid & 63;
    int quad = lane >> 4, r16 = lane & 15;
    int tq0 = blockIdx.x * 128, h = blockIdx.y, b = blockIdx.z;
    int kvh = h >> 2;
    const size_t rowb = QKVS * 2;

    // stage Q [128][64] into Vt region (xor-swizzled chunks of 16B)
    {
        const char* qb = (const char*)(qkv + (size_t)(b * Tn + tq0) * QKVS + h * 64);
        int rloc = lane >> 3, ch = (lane & 7) ^ rloc;
        #pragma unroll
        for (int i = 0; i < 4; ++i) {
            int r0 = wave * 8 + i * 32;
            __builtin_amdgcn_global_load_lds(
                (const __attribute__((address_space(1))) void*)(qb + (size_t)(r0 + rloc) * rowb + ch * 16),
                (__attribute__((address_space(3))) void*)((char*)Vt + r0 * 128), 16, 0, 0);
        }
    }
    __syncthreads();
    frag_ab qf[2][2];
    #pragma unroll
    for (int mt = 0; mt < 2; ++mt)
        #pragma unroll
        for (int ks = 0; ks < 2; ++ks) {
            int m = wave * 32 + mt * 16 + r16;
            int ch = (ks * 4 + quad) ^ (m & 7);
            qf[mt][ks] = *(const frag_ab*)((const char*)Vt + m * 128 + ch * 16);
        }

    float m_i[2][4], l_i[2][4];
    f32x4 O[2][4];
    #pragma unroll
    for (int mt = 0; mt < 2; ++mt) {
        #pragma unroll
        for (int r = 0; r < 4; ++r) { m_i[mt][r] = -1e30f; l_i[mt][r] = 0.f; }
        #pragma unroll
        for (int nt = 0; nt < 4; ++nt) O[mt][nt] = (f32x4){0.f, 0.f, 0.f, 0.f};
    }

    int nst = blockIdx.x + 1;
    for (int st = 0; st < nst; ++st) {
        int s0 = st * 128;
        __syncthreads();   // prior step's Ps/Vt/Ks reads (and qf loads) complete
        // stage K tile [128][64] swizzled
        {
            const char* kb = (const char*)(qkv + (size_t)(b * Tn + s0) * QKVS + 1024 + kvh * 64);
            int rloc = lane >> 3, ch = (lane & 7) ^ rloc;
            #pragma unroll
            for (int i = 0; i < 4; ++i) {
                int r0 = wave * 8 + i * 32;
                __builtin_amdgcn_global_load_lds(
                    (const __attribute__((address_space(1))) void*)(kb + (size_t)(r0 + rloc) * rowb + ch * 16),
                    (__attribute__((address_space(3))) void*)((char*)Ks + r0 * 128), 16, 0, 0);
            }
        }
        // stage V transposed [d][s] swizzled (pack 2 s into b32 writes)
        {
            const unsigned short* vb = qkv + (size_t)(b * Tn + s0) * QKVS + 1280 + kvh * 64;
            int d4 = (tid & 15) * 4;
            #pragma unroll
            for (int pass = 0; pass < 4; ++pass) {
                int sl = 8 * wave + 2 * (lane >> 4) + pass * 32;
                ushort4 v0 = *(const ushort4*)(vb + (size_t)sl * QKVS + d4);
                ushort4 v1 = *(const ushort4*)(vb + (size_t)(sl + 1) * QKVS + d4);
                unsigned short a0[4] = {v0.x, v0.y, v0.z, v0.w};
                unsigned short a1[4] = {v1.x, v1.y, v1.z, v1.w};
                #pragma unroll
                for (int i = 0; i < 4; ++i) {
                    int d = d4 + i;
                    int col = (((sl >> 3) ^ (d & 15)) << 3) | (sl & 7);
                    *(unsigned int*)(Vt + d * 128 + col) =
                        (unsigned int)a0[i] | ((unsigned int)a1[i] << 16);
                }
            }
        }
        __syncthreads();
        // S = Q K^T  (scale+log2e folded into Q)
        f32x4 Sacc[2][8];
        #pragma unroll
        for (int mt = 0; mt < 2; ++mt)
            #pragma unroll
            for (int nt = 0; nt < 8; ++nt) Sacc[mt][nt] = (f32x4){0.f, 0.f, 0.f, 0.f};
        #pragma unroll
        for (int ks = 0; ks < 2; ++ks) {
            frag_ab kf[8];
            #pragma unroll
            for (int nt = 0; nt < 8; ++nt) {
                int n = nt * 16 + r16;
                int ch = (ks * 4 + quad) ^ (n & 7);
                kf[nt] = *(const frag_ab*)((const char*)Ks + n * 128 + ch * 16);
            }
            #pragma unroll
            for (int mt = 0; mt < 2; ++mt)
                #pragma unroll
                for (int nt = 0; nt < 8; ++nt)
                    Sacc[mt][nt] = __builtin_amdgcn_mfma_f32_16x16x32_bf16(qf[mt][ks], kf[nt], Sacc[mt][nt], 0, 0, 0);
        }
        // causal mask (only possible on the diagonal step)
        if (st == nst - 1) {
            #pragma unroll
            for (int mt = 0; mt < 2; ++mt) {
                int trow = wave * 32 + mt * 16 + quad * 4;
                #pragma unroll
                for (int nt = 0; nt < 8; ++nt) {
                    int scol = nt * 16 + r16;
                    #pragma unroll
                    for (int r = 0; r < 4; ++r)
                        if (scol > trow + r) Sacc[mt][nt][r] = -1e30f;
                }
            }
        }
        // online softmax (base 2) + P -> LDS (swizzled, wave-private rows)
        #pragma unroll
        for (int mt = 0; mt < 2; ++mt) {
            float mx[4];
            #pragma unroll
            for (int r = 0; r < 4; ++r) {
                float m_ = Sacc[mt][0][r];
                #pragma unroll
                for (int nt = 1; nt < 8; ++nt) m_ = fmaxf(m_, Sacc[mt][nt][r]);
                mx[r] = m_;
            }
            #pragma unroll
            for (int off = 1; off < 16; off <<= 1)
                #pragma unroll
                for (int r = 0; r < 4; ++r) mx[r] = fmaxf(mx[r], __shfl_xor(mx[r], off));
            #pragma unroll
            for (int r = 0; r < 4; ++r) {
                float mn = fmaxf(m_i[mt][r], mx[r]);
                float al = exp2f(m_i[mt][r] - mn);
                m_i[mt][r] = mn;
                l_i[mt][r] *= al;
                #pragma unroll
                for (int nt = 0; nt < 4; ++nt) O[mt][nt][r] *= al;
            }
            float rsum[4] = {0.f, 0.f, 0.f, 0.f};
            #pragma unroll
            for (int nt = 0; nt < 8; ++nt)
                #pragma unroll
                for (int r = 0; r < 4; ++r) {
                    float pv = exp2f(Sacc[mt][nt][r] - m_i[mt][r]);
                    Sacc[mt][nt][r] = pv;
                    rsum[r] += pv;
                }
            #pragma unroll
            for (int off = 1; off < 16; off <<= 1)
                #pragma unroll
                for (int r = 0; r < 4; ++r) rsum[r] += __shfl_xor(rsum[r], off);
            #pragma unroll
            for (int r = 0; r < 4; ++r) l_i[mt][r] += rsum[r];
            #pragma unroll
            for (int nt = 0; nt < 8; ++nt) {
                int scol = nt * 16 + r16;
                int chb = scol >> 3;
                #pragma unroll
                for (int r = 0; r < 4; ++r) {
                    int m = wave * 32 + mt * 16 + quad * 4 + r;
                    int col = ((chb ^ (m & 15)) << 3) | (scol & 7);
                    Ps[m * 128 + col] = f2bf(Sacc[mt][nt][r]);
                }
            }
        }
        // O += P V   (P A-frags wave-private; lgkm ordering handled by compiler)
        #pragma unroll
        for (int ks = 0; ks < 4; ++ks) {
            frag_ab pa[2], vf[4];
            #pragma unroll
            for (int mt = 0; mt < 2; ++mt) {
                int m = wave * 32 + mt * 16 + r16;
                int ch = (ks * 4 + quad) ^ (m & 15);
                pa[mt] = *(const frag_ab*)((const char*)Ps + m * 256 + ch * 16);
            }
            #pragma unroll
            for (int nt = 0; nt < 4; ++nt) {
                int n = nt * 16 + r16;
                int ch = (ks * 4 + quad) ^ (n & 15);
                vf[nt] = *(const frag_ab*)((const char*)Vt + n * 256 + ch * 16);
            }
            #pragma unroll
            for (int mt = 0; mt < 2; ++mt)
                #pragma unroll
                for (int nt = 0; nt < 4; ++nt)
                    O[mt][nt] = __builtin_amdgcn_mfma_f32_16x16x32_bf16(pa[mt], vf[nt], O[mt][nt], 0, 0, 0);
        }
    }
    // epilogue: normalize, write bf16 attn [t][h*64+d]
    #pragma unroll
    for (int mt = 0; mt < 2; ++mt) {
        float inv[4];
        #pragma unroll
        for (int r = 0; r < 4; ++r) inv[r] = 1.f / l_i[mt][r];
        #pragma unroll
        for (int nt = 0; nt < 4; ++nt)
            #pragma unroll
            for (int r = 0; r < 4; ++r) {
                int t = tq0 + wave * 32 + mt * 16 + quad * 4 + r;
                int c = h * 64 + nt * 16 + r16;
                attnb[(size_t)(b * Tn + t) * Dm + c] = f2bf(O[mt][nt][r] * inv[r]);
            }
    }
}

// ---------------- Router ----------------
__global__ void router_kernel(const float* __restrict__ h2, const float* __restrict__ rw,
                              const float* __restrict__ rb, int* __restrict__ assign,
                              float* __restrict__ gate) {
    int t = blockIdx.x;
    __shared__ float row[Dm];
    __shared__ float logits[NE];
    for (int d = threadIdx.x; d < Dm; d += 512) row[d] = h2[(size_t)t * Dm + d];
    __syncthreads();
    int e = threadIdx.x >> 6, lane = threadIdx.x & 63;
    float part = 0.f;
    for (int d = lane; d < Dm; d += 64) part += row[d] * rw[(size_t)d * NE + e];
    for (int off = 32; off; off >>= 1) part += __shfl_down(part, off);
    if (lane == 0) logits[e] = part + rb[e];
    __syncthreads();
    if (threadIdx.x == 0) {
        int i0 = 0; float m0 = logits[0];
        for (int i = 1; i < NE; ++i) if (logits[i] > m0) { m0 = logits[i]; i0 = i; }
        int i1 = -1; float m1 = -1e30f;
        for (int i = 0; i < NE; ++i) if (i != i0 && logits[i] > m1) { m1 = logits[i]; i1 = i; }
        float e1 = __expf(m1 - m0);
        float s = 1.f + e1;
        assign[t * 2] = i0; assign[t * 2 + 1] = i1;
        gate[t * 2] = 1.f / s; gate[t * 2 + 1] = e1 / s;
    }
}

// ---------------- Capacity scan (single block) ----------------
__global__ void scan_kernel(const int* __restrict__ assign, int* __restrict__ pos,
                            int* __restrict__ limit) {
    __shared__ int cnt[256][16];
    __shared__ int tot[16];
    int tid = threadIdx.x;
    int local[16];
    #pragma unroll
    for (int i = 0; i < 16; ++i) local[i] = 0;
    for (int r = 0; r < 8; ++r) {
        int t = tid * 8 + r;
        local[assign[t * 2]]++;
        local[8 + assign[t * 2 + 1]]++;
    }
    #pragma unroll
    for (int i = 0; i < 16; ++i) cnt[tid][i] = local[i];
    __syncthreads();
    if (tid < 16) {
        int run = 0;
        for (int th = 0; th < 256; ++th) { int v = cnt[th][tid]; cnt[th][tid] = run; run += v; }
        tot[tid] = run;
    }
    __syncthreads();
    int r0[NE], r1[NE];
    #pragma unroll
    for (int e = 0; e < NE; ++e) { r0[e] = cnt[tid][e]; r1[e] = cnt[tid][8 + e]; }
    for (int r = 0; r < 8; ++r) {
        int t = tid * 8 + r;
        int e0 = assign[t * 2], e1 = assign[t * 2 + 1];
        r0[e0]++; pos[t * 2] = r0[e0];
        r1[e1]++; pos[t * 2 + 1] = r0[e1] + r1[e1];
    }
    if (tid == 0)
        for (int e = 0; e < NE; ++e) {
            int C = tot[e] + tot[8 + e];
            limit[e] = C < (CAPn - 1) ? C : (CAPn - 1);
        }
}

// ---------------- Dispatch (fp32 scatter-add; collisions sum per reference) ----------------
__global__ void dispatch_kernel(const float* __restrict__ h2, const int* __restrict__ assign,
                                const int* __restrict__ pos, float* __restrict__ grouped) {
    int slot = blockIdx.x;
    int p = pos[slot];
    if (p >= CAPn) return;
    int e = assign[slot];
    const float* src = h2 + (size_t)(slot >> 1) * Dm;
    float* dst = grouped + ((size_t)e * CAPn + p) * Dm;
    for (int d = threadIdx.x; d < Dm; d += 256) atomicAdd(&dst[d], src[d]);
}

// ---------------- fp32 -> bf16 elementwise convert ----------------
__global__ void convert_bf16(const float* __restrict__ in, unsigned short* __restrict__ out, int n4) {
    int i = blockIdx.x * 256 + threadIdx.x;
    if (i >= n4) return;
    float4 v = ((const float4*)in)[i];
    unsigned long long pk = (unsigned long long)f2bf(v.x)
                          | ((unsigned long long)f2bf(v.y) << 16)
                          | ((unsigned long long)f2bf(v.z) << 32)
                          | ((unsigned long long)f2bf(v.w) << 48);
    ((unsigned long long*)out)[i] = pk;
}

// ---------------- MoE bf16 MFMA GEMM (per-expert, limit-gated) ----------------
template<bool GELU>
__global__ __launch_bounds__(256) void mfma_gemm(const unsigned short* __restrict__ A,
                                                 const unsigned short* __restrict__ Bt,
                                                 unsigned short* __restrict__ C,
                                                 int N, int K, const int* __restrict__ limit) {
    int e = blockIdx.z;
    int m0 = blockIdx.y * 128;
    if (m0 > limit[e]) return;
    A  += (size_t)e * CAPn * K;
    Bt += (size_t)e * N * K;
    C  += (size_t)e * CAPn * N;
    int n0 = blockIdx.x * 128;
    __shared__ unsigned short As[128 * 32];
    __shared__ unsigned short Bs[128 * 32];
    int tid = threadIdx.x, wave = tid >> 6, lane = tid & 63;
    int quad = lane >> 4, r16 = lane & 15;
    int wm = wave & 1, wn = wave >> 1;
    f32x4 acc[4][4];
    #pragma unroll
    for (int mt = 0; mt < 4; ++mt)
        #pragma unroll
        for (int nt = 0; nt < 4; ++nt) acc[mt][nt] = (f32x4){0.f, 0.f, 0.f, 0.f};
    const size_t rs = (size_t)K * 2;
    const char* ga0 = (const char*)A  + (size_t)m0 * rs;
    const char* gb0 = (const char*)Bt + (size_t)n0 * rs;
    for (int kk = 0; kk < K; kk += 32) {
        __syncthreads();
        #pragma unroll
        for (int i = 0; i < 2; ++i) {
            int r = wave * 16 + i * 64 + (lane >> 2);
            size_t go = (size_t)r * rs + (size_t)kk * 2 + (lane & 3) * 16;
            int lofs = wave * 1024 + i * 4096;
            __builtin_amdgcn_global_load_lds(
                (const __attribute__((address_space(1))) void*)(ga0 + go),
                (__attribute__((address_space(3))) void*)((char*)As + lofs), 16, 0, 0);
            __builtin_amdgcn_global_load_lds(
                (const __attribute__((address_space(1))) void*)(gb0 + go),
                (__attribute__((address_space(3))) void*)((char*)Bs + lofs), 16, 0, 0);
        }
        __syncthreads();
        frag_ab a[4], b[4];
        #pragma unroll
        for (int t = 0; t < 4; ++t) {
            a[t] = *(const frag_ab*)((const char*)As + (wm * 64 + t * 16 + r16) * 64 + quad * 16);
            b[t] = *(const frag_ab*)((const char*)Bs + (wn * 64 + t * 16 + r16) * 64 + quad * 16);
        }
        #pragma unroll
        for (int mt = 0; mt < 4; ++mt)
            #pragma unroll
            for (int nt = 0; nt < 4; ++nt)
                acc[mt][nt] = __builtin_amdgcn_mfma_f32_16x16x32_bf16(a[mt], b[nt], acc[mt][nt], 0, 0, 0);
    }
    #pragma unroll
    for (int mt = 0; mt < 4; ++mt)
        #pragma unroll
        for (int nt = 0; nt < 4; ++nt)
            #pragma unroll
            for (int r = 0; r < 4; ++r) {
                int m = m0 + wm * 64 + mt * 16 + quad * 4 + r;
                int n = n0 + wn * 64 + nt * 16 + r16;
                size_t idx = (size_t)m * N + n;
                float v = acc[mt][nt][r];
                if (GELU) v = gelu_fast(v * bf2f(C[idx]));
                C[idx] = f2bf(v);
            }
}

// ---------------- Combine ----------------
__global__ void combine_kernel(const float* __restrict__ x2, const float* __restrict__ h2,
                               const unsigned short* __restrict__ eout, const int* __restrict__ assign,
                               const int* __restrict__ pos, const float* __restrict__ gate,
                               float* __restrict__ out) {
    int t = blockIdx.x;
    int e0 = assign[t * 2], e1 = assign[t * 2 + 1];
    int p0 = pos[t * 2],   p1 = pos[t * 2 + 1];
    float g0 = gate[t * 2], g1 = gate[t * 2 + 1];
    bool k0 = p0 < CAPn, k1 = p1 < CAPn;
    const unsigned short* s0 = eout + ((size_t)e0 * CAPn + p0) * Dm;
    const unsigned short* s1 = eout + ((size_t)e1 * CAPn + p1) * Dm;
    const float* hb = h2 + (size_t)t * Dm;
    for (int d = threadIdx.x; d < Dm; d += 256) {
        float v0 = k0 ? bf2f(s0[d]) : hb[d];
        float v1 = k1 ? bf2f(s1[d]) : hb[d];
        out[(size_t)t * Dm + d] = x2[(size_t)t * Dm + d] + g0 * v0 + g1 * v1;
    }
}

extern "C" void kernel_launch(void* const* d_in, const int* in_sizes, int n_in,
                              void* d_out, int out_size, void* d_ws, size_t ws_size,
                              hipStream_t stream) {
    const float* x        = (const float*)d_in[0];
    const float* wq       = (const float*)d_in[1];
    const float* wk       = (const float*)d_in[2];
    const float* wv       = (const float*)d_in[3];
    const float* wo       = (const float*)d_in[4];
    const float* router_w = (const float*)d_in[5];
    const float* router_b = (const float*)d_in[6];
    const float* w1       = (const float*)d_in[7];
    const float* w2       = (const float*)d_in[8];
    const float* w3       = (const float*)d_in[9];
    const float* n1s      = (const float*)d_in[10];
    const float* n2s      = (const float*)d_in[11];
    float* out = (float*)d_out;
    unsigned char* ws = (unsigned char*)d_ws;
    const size_t MB = 1ull << 20;

    // Workspace (peak 113 MB, timeline-aliased):
    //  attn phase:  h_bf[0,4) qkv[4,10) wqkvt[10,13) attnb[13,17) wot[17,19)
    //  MoE phase:   grouped_f32[0,32) -> tmp1/hh bf16 [0,32)
    //  persistent:  x2[32,40) h2[40,48) small[48..] grouped_bf[49,65) wtslot[65,97) eout[97,113)
    unsigned short* h_bf  = (unsigned short*)(ws + 0 * MB);
    unsigned short* qkv   = (unsigned short*)(ws + 4 * MB);
    unsigned short* wqkvt = (unsigned short*)(ws + 10 * MB);
    unsigned short* attnb = (unsigned short*)(ws + 13 * MB);
    unsigned short* wot   = (unsigned short*)(ws + 17 * MB);
    float* grouped_f32    = (float*)(ws + 0 * MB);
    unsigned short* tmp1hh = (unsigned short*)(ws + 0 * MB);
    float* x2      = (float*)(ws + 32 * MB);
    float* h2      = (float*)(ws + 40 * MB);
    int*   assign  = (int*)  (ws + 48 * MB);
    int*   pos     = (int*)  (ws + 48 * MB + 65536);
    float* gate    = (float*)(ws + 48 * MB + 131072);
    int*   limit   = (int*)  (ws + 48 * MB + 196608);
    unsigned short* grouped_bf = (unsigned short*)(ws + 49 * MB);
    unsigned short* wtslot     = (unsigned short*)(ws + 65 * MB);
    unsigned short* eout       = (unsigned short*)(ws + 97 * MB);
    (void)in_sizes; (void)n_in; (void)out_size; (void)ws_size;

    // ---- attention half (bf16 MFMA) ----
    transpose_convert<<<dim3(16, 16, 1), 256, 0, stream>>>(wq, wqkvt, Dm, Dm);
    transpose_convert<<<dim3(4, 16, 1), 256, 0, stream>>>(wk, wqkvt + 1024 * 1024, Dm, 256);
    transpose_convert<<<dim3(4, 16, 1), 256, 0, stream>>>(wv, wqkvt + 1280 * 1024, Dm, 256);
    transpose_convert<<<dim3(16, 16, 1), 256, 0, stream>>>(wo, wot, Dm, Dm);
    rmsnorm_kernel<1><<<NTOK, 256, 0, stream>>>(x, n1s, h_bf);
    mfma_gemm2<0><<<dim3(QKVS / 128, NTOK / 128), 256, 0, stream>>>(h_bf, wqkvt, qkv, nullptr, QKVS, Dm);
    rope_bf16<<<(NTOK * (HQn + HKVn) * 32) / 256, 256, 0, stream>>>(qkv);
    mfma_attn<<<dim3(Tn / 128, HQn, Bn), 256, 0, stream>>>(qkv, attnb);
    mfma_gemm2<1><<<dim3(Dm / 128, NTOK / 128), 256, 0, stream>>>(attnb, wot, x2, x, Dm, Dm);
    // ---- MoE half ----
    rmsnorm_kernel<0><<<NTOK, 256, 0, stream>>>(x2, n2s, h2);
    router_kernel<<<NTOK, 512, 0, stream>>>(h2, router_w, router_b, assign, gate);
    scan_kernel<<<1, 256, 0, stream>>>(assign, pos, limit);
    hipMemsetAsync(grouped_f32, 0, (size_t)NE * CAPn * Dm * sizeof(float), stream);
    dispatch_kernel<<<NTOK * 2, 256, 0, stream>>>(h2, assign, pos, grouped_f32);
    convert_bf16<<<(NE * CAPn * Dm / 4 + 255) / 256, 256, 0, stream>>>(grouped_f32, grouped_bf, NE * CAPn * Dm / 4);
    transpose_convert<<<dim3(HIDn / 64, Dm / 64, NE), 256, 0, stream>>>(w1, wtslot, Dm, HIDn);
    mfma_gemm<false><<<dim3(HIDn / 128, CAPn / 128, NE), 256, 0, stream>>>(grouped_bf, wtslot, tmp1hh, HIDn, Dm, limit);
    transpose_convert<<<dim3(HIDn / 64, Dm / 64, NE), 256, 0, stream>>>(w2, wtslot, Dm, HIDn);
    mfma_gemm<true><<<dim3(HIDn / 128, CAPn / 128, NE), 256, 0, stream>>>(grouped_bf, wtslot, tmp1hh, HIDn, Dm, limit);
    transpose_convert<<<dim3(Dm / 64, HIDn / 64, NE), 256, 0, stream>>>(w3, wtslot, HIDn, Dm);
    mfma_gemm<false><<<dim3(Dm / 128, CAPn / 128, NE), 256, 0, stream>>>(tmp1hh, wtslot, eout, Dm, HIDn, limit);
    combine_kernel<<<NTOK, 256, 0, stream>>>(x2, h2, eout, assign, pos, gate, out);
}

// Round 7
// 564.496 us; speedup vs baseline: 3.7875x; 1.0092x over previous
//
#include <hip/hip_runtime.h>
#include <math.h>

#define Dm 1024
#define Tn 1024
#define Bn 2
#define NTOK 2048
#define HQn 16
#define HKVn 4
#define KDn 64
#define VDn 64
#define Gn 4
#define NE 8
#define CAPn 1024
#define HIDn 2048
#define QKVS 1536   // qkv row stride (elems): q[0,1024) k[1024,1280) v[1280,1536)

using frag_ab = __attribute__((ext_vector_type(8))) short;   // 8 bf16
using f32x4  = __attribute__((ext_vector_type(4))) float;

__device__ __forceinline__ unsigned short f2bf(float f) {
    union { float f; unsigned int u; } v; v.f = f;
    unsigned int r = v.u + 0x7FFFu + ((v.u >> 16) & 1u);
    return (unsigned short)(r >> 16);
}
__device__ __forceinline__ float bf2f(unsigned short b) {
    union { unsigned int u; float f; } v; v.u = ((unsigned int)b) << 16;
    return v.f;
}
__device__ __forceinline__ float gelu_fast(float y) {
    float z = 0.7978845608028654f * (y + 0.044715f * y * y * y);
    float az = fabsf(z);
    float t = __expf(-2.f * az);
    float th = (1.f - t) / (1.f + t);
    th = copysignf(th, z);
    return 0.5f * y * (1.f + th);
}

// ---------------- RMSNorm (bf16 out, attention pre-norm) ----------------
__global__ void rmsnorm_bf16_kernel(const float* __restrict__ x, const float* __restrict__ scale,
                                    unsigned short* __restrict__ out) {
    int row = blockIdx.x;
    const float* xr = x + (size_t)row * Dm;
    float ss = 0.f;
    for (int d = threadIdx.x; d < Dm; d += 256) { float v = xr[d]; ss += v * v; }
    __shared__ float red[256];
    red[threadIdx.x] = ss; __syncthreads();
    for (int s = 128; s > 0; s >>= 1) {
        if (threadIdx.x < s) red[threadIdx.x] += red[threadIdx.x + s];
        __syncthreads();
    }
    float inv = rsqrtf(red[0] * (1.f / Dm) + 1e-6f);
    for (int d = threadIdx.x; d < Dm; d += 256)
        out[(size_t)row * Dm + d] = f2bf(xr[d] * inv * scale[d]);
}

// ---------------- Fused RMSNorm (fp32 h2 out) + router logits + top-2 gates ----------------
// Value-identical to the previous rmsnorm<0> + router pair: h2 written the same,
// logits computed from the same fp32 normed row (LDS-resident instead of re-read).
__global__ void rmsnorm_router_kernel(const float* __restrict__ x2, const float* __restrict__ scale,
                                      const float* __restrict__ rw, const float* __restrict__ rb,
                                      float* __restrict__ h2, int* __restrict__ assign,
                                      float* __restrict__ gate) {
    int row = blockIdx.x;
    const float* xr = x2 + (size_t)row * Dm;
    __shared__ float red[256];
    __shared__ float rowbuf[Dm];
    __shared__ float logits[NE];
    float v4[4]; float ss = 0.f;
    #pragma unroll
    for (int i = 0; i < 4; ++i) { v4[i] = xr[threadIdx.x + 256 * i]; ss += v4[i] * v4[i]; }
    red[threadIdx.x] = ss; __syncthreads();
    for (int s = 128; s > 0; s >>= 1) {
        if (threadIdx.x < s) red[threadIdx.x] += red[threadIdx.x + s];
        __syncthreads();
    }
    float inv = rsqrtf(red[0] * (1.f / Dm) + 1e-6f);
    #pragma unroll
    for (int i = 0; i < 4; ++i) {
        int d = threadIdx.x + 256 * i;
        float h = v4[i] * inv * scale[d];
        h2[(size_t)row * Dm + d] = h;
        rowbuf[d] = h;
    }
    __syncthreads();
    int e = threadIdx.x >> 5, lane32 = threadIdx.x & 31;
    float part = 0.f;
    for (int d = lane32; d < Dm; d += 32) part += rowbuf[d] * rw[(size_t)d * NE + e];
    for (int off = 16; off; off >>= 1) part += __shfl_down(part, off, 32);
    if (lane32 == 0) logits[e] = part + rb[e];
    __syncthreads();
    if (threadIdx.x == 0) {
        int i0 = 0; float m0 = logits[0];
        for (int i = 1; i < NE; ++i) if (logits[i] > m0) { m0 = logits[i]; i0 = i; }
        int i1 = -1; float m1 = -1e30f;
        for (int i = 0; i < NE; ++i) if (i != i0 && logits[i] > m1) { m1 = logits[i]; i1 = i; }
        float e1 = __expf(m1 - m0);
        float s = 1.f + e1;
        assign[row * 2] = i0; assign[row * 2 + 1] = i1;
        gate[row * 2] = 1.f / s; gate[row * 2 + 1] = e1 / s;
    }
}

// ---------------- fp32 [R][C] -> bf16 [C][R] transpose+convert (z = expert or 1) ----------------
__global__ void transpose_convert(const float* __restrict__ in, unsigned short* __restrict__ out,
                                  int R, int Ccols) {
    int e = blockIdx.z;
    in  += (size_t)e * R * Ccols;
    out += (size_t)e * R * Ccols;
    __shared__ float T[64][65];
    int tid = threadIdx.x;
    int r0 = blockIdx.y * 64, c0 = blockIdx.x * 64;
    #pragma unroll
    for (int rep = 0; rep < 4; ++rep) {
        int r = (tid >> 4) + rep * 16;
        int c = (tid & 15) * 4;
        float4 v = *(const float4*)(in + (size_t)(r0 + r) * Ccols + c0 + c);
        T[r][c] = v.x; T[r][c + 1] = v.y; T[r][c + 2] = v.z; T[r][c + 3] = v.w;
    }
    __syncthreads();
    #pragma unroll
    for (int rep = 0; rep < 4; ++rep) {
        int c = rep * 16 + (tid >> 4);
        int r = (tid & 15) * 4;
        unsigned long long pk = (unsigned long long)f2bf(T[r][c])
                              | ((unsigned long long)f2bf(T[r + 1][c]) << 16)
                              | ((unsigned long long)f2bf(T[r + 2][c]) << 32)
                              | ((unsigned long long)f2bf(T[r + 3][c]) << 48);
        *(unsigned long long*)(out + (size_t)(c0 + c) * R + r0 + r) = pk;
    }
}

// ---------------- generic bf16 MFMA GEMM: C[m][n] = A[m][k] @ Bt[n][k]^T ----------------
// MODE 0: bf16 C.  MODE 1: fp32 C = acc + R (residual).
template<int MODE>
__global__ __launch_bounds__(256) void mfma_gemm2(const unsigned short* __restrict__ A,
                                                  const unsigned short* __restrict__ Bt,
                                                  void* __restrict__ Cout,
                                                  const float* __restrict__ R,
                                                  int N, int K) {
    int m0 = blockIdx.y * 128, n0 = blockIdx.x * 128;
    __shared__ unsigned short As[128 * 32];
    __shared__ unsigned short Bs[128 * 32];
    int tid = threadIdx.x, wave = tid >> 6, lane = tid & 63;
    int quad = lane >> 4, r16 = lane & 15;
    int wm = wave & 1, wn = wave >> 1;
    f32x4 acc[4][4];
    #pragma unroll
    for (int mt = 0; mt < 4; ++mt)
        #pragma unroll
        for (int nt = 0; nt < 4; ++nt) acc[mt][nt] = (f32x4){0.f, 0.f, 0.f, 0.f};
    const size_t rs = (size_t)K * 2;
    const char* ga0 = (const char*)A  + (size_t)m0 * rs;
    const char* gb0 = (const char*)Bt + (size_t)n0 * rs;
    for (int kk = 0; kk < K; kk += 32) {
        __syncthreads();
        #pragma unroll
        for (int i = 0; i < 2; ++i) {
            int r = wave * 16 + i * 64 + (lane >> 2);
            size_t go = (size_t)r * rs + (size_t)kk * 2 + (lane & 3) * 16;
            int lofs = wave * 1024 + i * 4096;
            __builtin_amdgcn_global_load_lds(
                (const __attribute__((address_space(1))) void*)(ga0 + go),
                (__attribute__((address_space(3))) void*)((char*)As + lofs), 16, 0, 0);
            __builtin_amdgcn_global_load_lds(
                (const __attribute__((address_space(1))) void*)(gb0 + go),
                (__attribute__((address_space(3))) void*)((char*)Bs + lofs), 16, 0, 0);
        }
        __syncthreads();
        frag_ab a[4], b[4];
        #pragma unroll
        for (int t = 0; t < 4; ++t) {
            a[t] = *(const frag_ab*)((const char*)As + (wm * 64 + t * 16 + r16) * 64 + quad * 16);
            b[t] = *(const frag_ab*)((const char*)Bs + (wn * 64 + t * 16 + r16) * 64 + quad * 16);
        }
        #pragma unroll
        for (int mt = 0; mt < 4; ++mt)
            #pragma unroll
            for (int nt = 0; nt < 4; ++nt)
                acc[mt][nt] = __builtin_amdgcn_mfma_f32_16x16x32_bf16(a[mt], b[nt], acc[mt][nt], 0, 0, 0);
    }
    #pragma unroll
    for (int mt = 0; mt < 4; ++mt)
        #pragma unroll
        for (int nt = 0; nt < 4; ++nt)
            #pragma unroll
            for (int r = 0; r < 4; ++r) {
                int m = m0 + wm * 64 + mt * 16 + quad * 4 + r;
                int n = n0 + wn * 64 + nt * 16 + r16;
                size_t idx = (size_t)m * N + n;
                float v = acc[mt][nt][r];
                if (MODE == 0) ((unsigned short*)Cout)[idx] = f2bf(v);
                else           ((float*)Cout)[idx] = v + R[idx];
            }
}

// ---------------- RoPE on bf16 qkv (in place); q pre-scaled by 0.125*log2e ----------------
__global__ void rope_bf16(unsigned short* __restrict__ p) {
    int idx = blockIdx.x * 256 + threadIdx.x;
    const int QC = NTOK * HQn * 32;
    int i, col, row; float scale;
    if (idx < QC) {
        i = idx & 31; int h = (idx >> 5) & 15; row = idx >> 9;
        col = h * 64 + i; scale = 0.18033688011112042f;  // 0.125 * log2(e)
    } else {
        int r = idx - QC;
        i = r & 31; int h = (r >> 5) & 3; row = r >> 7;
        col = 1024 + h * 64 + i; scale = 1.f;
    }
    int t = row & (Tn - 1);
    size_t base = (size_t)row * QKVS + col;
    float theta = __expf(-(float)i * (1.f / 32.f) * 9.210340371976184f); // 10000^(-i/32)
    float ang = (float)t * theta;
    float c = cosf(ang), s = sinf(ang);
    float x1 = bf2f(p[base]), x2 = bf2f(p[base + 32]);
    p[base]      = f2bf((x1 * c - x2 * s) * scale);
    p[base + 32] = f2bf((x2 * c + x1 * s) * scale);
}

// ---------------- MFMA flash attention ----------------
// grid (Tn/128, HQn, Bn), 256 thr = 4 waves x 32 q-rows. S-steps of 128 cols.
__global__ __launch_bounds__(256) void mfma_attn(const unsigned short* __restrict__ qkv,
                                                 unsigned short* __restrict__ attnb) {
    __shared__ unsigned short lds[32768];
    unsigned short* Ps = lds;
    unsigned short* Ks = lds + 16384;
    unsigned short* Vt = lds + 24576;
    int tid = threadIdx.x, wave = tid >> 6, lane = tid & 63;
    int quad = lane >> 4, r16 = lane & 15;
    int tq0 = blockIdx.x * 128, h = blockIdx.y, b = blockIdx.z;
    int kvh = h >> 2;
    const size_t rowb = QKVS * 2;

    {
        const char* qb = (const char*)(qkv + (size_t)(b * Tn + tq0) * QKVS + h * 64);
        int rloc = lane >> 3, ch = (lane & 7) ^ rloc;
        #pragma unroll
        for (int i = 0; i < 4; ++i) {
            int r0 = wave * 8 + i * 32;
            __builtin_amdgcn_global_load_lds(
                (const __attribute__((address_space(1))) void*)(qb + (size_t)(r0 + rloc) * rowb + ch * 16),
                (__attribute__((address_space(3))) void*)((char*)Vt + r0 * 128), 16, 0, 0);
        }
    }
    __syncthreads();
    frag_ab qf[2][2];
    #pragma unroll
    for (int mt = 0; mt < 2; ++mt)
        #pragma unroll
        for (int ks = 0; ks < 2; ++ks) {
            int m = wave * 32 + mt * 16 + r16;
            int ch = (ks * 4 + quad) ^ (m & 7);
            qf[mt][ks] = *(const frag_ab*)((const char*)Vt + m * 128 + ch * 16);
        }

    float m_i[2][4], l_i[2][4];
    f32x4 O[2][4];
    #pragma unroll
    for (int mt = 0; mt < 2; ++mt) {
        #pragma unroll
        for (int r = 0; r < 4; ++r) { m_i[mt][r] = -1e30f; l_i[mt][r] = 0.f; }
        #pragma unroll
        for (int nt = 0; nt < 4; ++nt) O[mt][nt] = (f32x4){0.f, 0.f, 0.f, 0.f};
    }

    int nst = blockIdx.x + 1;
    for (int st = 0; st < nst; ++st) {
        int s0 = st * 128;
        __syncthreads();
        {
            const char* kb = (const char*)(qkv + (size_t)(b * Tn + s0) * QKVS + 1024 + kvh * 64);
            int rloc = lane >> 3, ch = (lane & 7) ^ rloc;
            #pragma unroll
            for (int i = 0; i < 4; ++i) {
                int r0 = wave * 8 + i * 32;
                __builtin_amdgcn_global_load_lds(
                    (const __attribute__((address_space(1))) void*)(kb + (size_t)(r0 + rloc) * rowb + ch * 16),
                    (__attribute__((address_space(3))) void*)((char*)Ks + r0 * 128), 16, 0, 0);
            }
        }
        {
            const unsigned short* vb = qkv + (size_t)(b * Tn + s0) * QKVS + 1280 + kvh * 64;
            int d4 = (tid & 15) * 4;
            #pragma unroll
            for (int pass = 0; pass < 4; ++pass) {
                int sl = 8 * wave + 2 * (lane >> 4) + pass * 32;
                ushort4 v0 = *(const ushort4*)(vb + (size_t)sl * QKVS + d4);
                ushort4 v1 = *(const ushort4*)(vb + (size_t)(sl + 1) * QKVS + d4);
                unsigned short a0[4] = {v0.x, v0.y, v0.z, v0.w};
                unsigned short a1[4] = {v1.x, v1.y, v1.z, v1.w};
                #pragma unroll
                for (int i = 0; i < 4; ++i) {
                    int d = d4 + i;
                    int col = (((sl >> 3) ^ (d & 15)) << 3) | (sl & 7);
                    *(unsigned int*)(Vt + d * 128 + col) =
                        (unsigned int)a0[i] | ((unsigned int)a1[i] << 16);
                }
            }
        }
        __syncthreads();
        f32x4 Sacc[2][8];
        #pragma unroll
        for (int mt = 0; mt < 2; ++mt)
            #pragma unroll
            for (int nt = 0; nt < 8; ++nt) Sacc[mt][nt] = (f32x4){0.f, 0.f, 0.f, 0.f};
        #pragma unroll
        for (int ks = 0; ks < 2; ++ks) {
            frag_ab kf[8];
            #pragma unroll
            for (int nt = 0; nt < 8; ++nt) {
                int n = nt * 16 + r16;
                int ch = (ks * 4 + quad) ^ (n & 7);
                kf[nt] = *(const frag_ab*)((const char*)Ks + n * 128 + ch * 16);
            }
            #pragma unroll
            for (int mt = 0; mt < 2; ++mt)
                #pragma unroll
                for (int nt = 0; nt < 8; ++nt)
                    Sacc[mt][nt] = __builtin_amdgcn_mfma_f32_16x16x32_bf16(qf[mt][ks], kf[nt], Sacc[mt][nt], 0, 0, 0);
        }
        if (st == nst - 1) {
            #pragma unroll
            for (int mt = 0; mt < 2; ++mt) {
                int trow = wave * 32 + mt * 16 + quad * 4;
                #pragma unroll
                for (int nt = 0; nt < 8; ++nt) {
                    int scol = nt * 16 + r16;
                    #pragma unroll
                    for (int r = 0; r < 4; ++r)
                        if (scol > trow + r) Sacc[mt][nt][r] = -1e30f;
                }
            }
        }
        #pragma unroll
        for (int mt = 0; mt < 2; ++mt) {
            float mx[4];
            #pragma unroll
            for (int r = 0; r < 4; ++r) {
                float m_ = Sacc[mt][0][r];
                #pragma unroll
                for (int nt = 1; nt < 8; ++nt) m_ = fmaxf(m_, Sacc[mt][nt][r]);
                mx[r] = m_;
            }
            #pragma unroll
            for (int off = 1; off < 16; off <<= 1)
                #pragma unroll
                for (int r = 0; r < 4; ++r) mx[r] = fmaxf(mx[r], __shfl_xor(mx[r], off));
            #pragma unroll
            for (int r = 0; r < 4; ++r) {
                float mn = fmaxf(m_i[mt][r], mx[r]);
                float al = exp2f(m_i[mt][r] - mn);
                m_i[mt][r] = mn;
                l_i[mt][r] *= al;
                #pragma unroll
                for (int nt = 0; nt < 4; ++nt) O[mt][nt][r] *= al;
            }
            float rsum[4] = {0.f, 0.f, 0.f, 0.f};
            #pragma unroll
            for (int nt = 0; nt < 8; ++nt)
                #pragma unroll
                for (int r = 0; r < 4; ++r) {
                    float pv = exp2f(Sacc[mt][nt][r] - m_i[mt][r]);
                    Sacc[mt][nt][r] = pv;
                    rsum[r] += pv;
                }
            #pragma unroll
            for (int off = 1; off < 16; off <<= 1)
                #pragma unroll
                for (int r = 0; r < 4; ++r) rsum[r] += __shfl_xor(rsum[r], off);
            #pragma unroll
            for (int r = 0; r < 4; ++r) l_i[mt][r] += rsum[r];
            #pragma unroll
            for (int nt = 0; nt < 8; ++nt) {
                int scol = nt * 16 + r16;
                int chb = scol >> 3;
                #pragma unroll
                for (int r = 0; r < 4; ++r) {
                    int m = wave * 32 + mt * 16 + quad * 4 + r;
                    int col = ((chb ^ (m & 15)) << 3) | (scol & 7);
                    Ps[m * 128 + col] = f2bf(Sacc[mt][nt][r]);
                }
            }
        }
        #pragma unroll
        for (int ks = 0; ks < 4; ++ks) {
            frag_ab pa[2], vf[4];
            #pragma unroll
            for (int mt = 0; mt < 2; ++mt) {
                int m = wave * 32 + mt * 16 + r16;
                int ch = (ks * 4 + quad) ^ (m & 15);
                pa[mt] = *(const frag_ab*)((const char*)Ps + m * 256 + ch * 16);
            }
            #pragma unroll
            for (int nt = 0; nt < 4; ++nt) {
                int n = nt * 16 + r16;
                int ch = (ks * 4 + quad) ^ (n & 15);
                vf[nt] = *(const frag_ab*)((const char*)Vt + n * 256 + ch * 16);
            }
            #pragma unroll
            for (int mt = 0; mt < 2; ++mt)
                #pragma unroll
                for (int nt = 0; nt < 4; ++nt)
                    O[mt][nt] = __builtin_amdgcn_mfma_f32_16x16x32_bf16(pa[mt], vf[nt], O[mt][nt], 0, 0, 0);
        }
    }
    #pragma unroll
    for (int mt = 0; mt < 2; ++mt) {
        float inv[4];
        #pragma unroll
        for (int r = 0; r < 4; ++r) inv[r] = 1.f / l_i[mt][r];
        #pragma unroll
        for (int nt = 0; nt < 4; ++nt)
            #pragma unroll
            for (int r = 0; r < 4; ++r) {
                int t = tq0 + wave * 32 + mt * 16 + quad * 4 + r;
                int c = h * 64 + nt * 16 + r16;
                attnb[(size_t)(b * Tn + t) * Dm + c] = f2bf(O[mt][nt][r] * inv[r]);
            }
    }
}

// ---------------- Capacity scan (single block) ----------------
__global__ void scan_kernel(const int* __restrict__ assign, int* __restrict__ pos,
                            int* __restrict__ limit) {
    __shared__ int cnt[256][16];
    __shared__ int tot[16];
    int tid = threadIdx.x;
    int local[16];
    #pragma unroll
    for (int i = 0; i < 16; ++i) local[i] = 0;
    for (int r = 0; r < 8; ++r) {
        int t = tid * 8 + r;
        local[assign[t * 2]]++;
        local[8 + assign[t * 2 + 1]]++;
    }
    #pragma unroll
    for (int i = 0; i < 16; ++i) cnt[tid][i] = local[i];
    __syncthreads();
    if (tid < 16) {
        int run = 0;
        for (int th = 0; th < 256; ++th) { int v = cnt[th][tid]; cnt[th][tid] = run; run += v; }
        tot[tid] = run;
    }
    __syncthreads();
    int r0[NE], r1[NE];
    #pragma unroll
    for (int e = 0; e < NE; ++e) { r0[e] = cnt[tid][e]; r1[e] = cnt[tid][8 + e]; }
    for (int r = 0; r < 8; ++r) {
        int t = tid * 8 + r;
        int e0 = assign[t * 2], e1 = assign[t * 2 + 1];
        r0[e0]++; pos[t * 2] = r0[e0];
        r1[e1]++; pos[t * 2 + 1] = r0[e1] + r1[e1];
    }
    if (tid == 0)
        for (int e = 0; e < NE; ++e) {
            int C = tot[e] + tot[8 + e];
            limit[e] = C < (CAPn - 1) ? C : (CAPn - 1);
        }
}

// ---------------- Dispatch (fp32 scatter-add onto zeroed buffer) ----------------
// grouped MUST be zeroed first: it aliases attention-phase buffers (not 0xAA),
// and collision slots need exact sum semantics (R5 post-mortem).
__global__ void dispatch_kernel(const float* __restrict__ h2, const int* __restrict__ assign,
                                const int* __restrict__ pos, float* __restrict__ grouped) {
    int slot = blockIdx.x;
    int p = pos[slot];
    if (p >= CAPn) return;
    int e = assign[slot];
    const float* src = h2 + (size_t)(slot >> 1) * Dm;
    float* dst = grouped + ((size_t)e * CAPn + p) * Dm;
    for (int d = threadIdx.x; d < Dm; d += 256) atomicAdd(&dst[d], src[d]);
}

// ---------------- fp32 -> bf16 elementwise convert ----------------
__global__ void convert_bf16(const float* __restrict__ in, unsigned short* __restrict__ out, int n4) {
    int i = blockIdx.x * 256 + threadIdx.x;
    if (i >= n4) return;
    float4 v = ((const float4*)in)[i];
    unsigned long long pk = (unsigned long long)f2bf(v.x)
                          | ((unsigned long long)f2bf(v.y) << 16)
                          | ((unsigned long long)f2bf(v.z) << 32)
                          | ((unsigned long long)f2bf(v.w) << 48);
    ((unsigned long long*)out)[i] = pk;
}

// ---------------- MoE bf16 MFMA GEMM (per-expert, limit-gated) — round-4 proven ----------------
template<bool GELU>
__global__ __launch_bounds__(256) void mfma_gemm(const unsigned short* __restrict__ A,
                                                 const unsigned short* __restrict__ Bt,
                                                 unsigned short* __restrict__ C,
                                                 int N, int K, const int* __restrict__ limit) {
    int e = blockIdx.z;
    int m0 = blockIdx.y * 128;
    if (m0 > limit[e]) return;
    A  += (size_t)e * CAPn * K;
    Bt += (size_t)e * N * K;
    C  += (size_t)e * CAPn * N;
    int n0 = blockIdx.x * 128;
    __shared__ unsigned short As[128 * 32];
    __shared__ unsigned short Bs[128 * 32];
    int tid = threadIdx.x, wave = tid >> 6, lane = tid & 63;
    int quad = lane >> 4, r16 = lane & 15;
    int wm = wave & 1, wn = wave >> 1;
    f32x4 acc[4][4];
    #pragma unroll
    for (int mt = 0; mt < 4; ++mt)
        #pragma unroll
        for (int nt = 0; nt < 4; ++nt) acc[mt][nt] = (f32x4){0.f, 0.f, 0.f, 0.f};
    const size_t rs = (size_t)K * 2;
    const char* ga0 = (const char*)A  + (size_t)m0 * rs;
    const char* gb0 = (const char*)Bt + (size_t)n0 * rs;
    for (int kk = 0; kk < K; kk += 32) {
        __syncthreads();
        #pragma unroll
        for (int i = 0; i < 2; ++i) {
            int r = wave * 16 + i * 64 + (lane >> 2);
            size_t go = (size_t)r * rs + (size_t)kk * 2 + (lane & 3) * 16;
            int lofs = wave * 1024 + i * 4096;
            __builtin_amdgcn_global_load_lds(
                (const __attribute__((address_space(1))) void*)(ga0 + go),
                (__attribute__((address_space(3))) void*)((char*)As + lofs), 16, 0, 0);
            __builtin_amdgcn_global_load_lds(
                (const __attribute__((address_space(1))) void*)(gb0 + go),
                (__attribute__((address_space(3))) void*)((char*)Bs + lofs), 16, 0, 0);
        }
        __syncthreads();
        frag_ab a[4], b[4];
        #pragma unroll
        for (int t = 0; t < 4; ++t) {
            a[t] = *(const frag_ab*)((const char*)As + (wm * 64 + t * 16 + r16) * 64 + quad * 16);
            b[t] = *(const frag_ab*)((const char*)Bs + (wn * 64 + t * 16 + r16) * 64 + quad * 16);
        }
        #pragma unroll
        for (int mt = 0; mt < 4; ++mt)
            #pragma unroll
            for (int nt = 0; nt < 4; ++nt)
                acc[mt][nt] = __builtin_amdgcn_mfma_f32_16x16x32_bf16(a[mt], b[nt], acc[mt][nt], 0, 0, 0);
    }
    #pragma unroll
    for (int mt = 0; mt < 4; ++mt)
        #pragma unroll
        for (int nt = 0; nt < 4; ++nt)
            #pragma unroll
            for (int r = 0; r < 4; ++r) {
                int m = m0 + wm * 64 + mt * 16 + quad * 4 + r;
                int n = n0 + wn * 64 + nt * 16 + r16;
                size_t idx = (size_t)m * N + n;
                float v = acc[mt][nt][r];
                if (GELU) v = gelu_fast(v * bf2f(C[idx]));
                C[idx] = f2bf(v);
            }
}

// ---------------- Combine ----------------
__global__ void combine_kernel(const float* __restrict__ x2, const float* __restrict__ h2,
                               const unsigned short* __restrict__ eout, const int* __restrict__ assign,
                               const int* __restrict__ pos, const float* __restrict__ gate,
                               float* __restrict__ out) {
    int t = blockIdx.x;
    int e0 = assign[t * 2], e1 = assign[t * 2 + 1];
    int p0 = pos[t * 2],   p1 = pos[t * 2 + 1];
    float g0 = gate[t * 2], g1 = gate[t * 2 + 1];
    bool k0 = p0 < CAPn, k1 = p1 < CAPn;
    const unsigned short* s0 = eout + ((size_t)e0 * CAPn + p0) * Dm;
    const unsigned short* s1 = eout + ((size_t)e1 * CAPn + p1) * Dm;
    const float* hb = h2 + (size_t)t * Dm;
    for (int d = threadIdx.x; d < Dm; d += 256) {
        float v0 = k0 ? bf2f(s0[d]) : hb[d];
        float v1 = k1 ? bf2f(s1[d]) : hb[d];
        out[(size_t)t * Dm + d] = x2[(size_t)t * Dm + d] + g0 * v0 + g1 * v1;
    }
}

extern "C" void kernel_launch(void* const* d_in, const int* in_sizes, int n_in,
                              void* d_out, int out_size, void* d_ws, size_t ws_size,
                              hipStream_t stream) {
    const float* x        = (const float*)d_in[0];
    const float* wq       = (const float*)d_in[1];
    const float* wk       = (const float*)d_in[2];
    const float* wv       = (const float*)d_in[3];
    const float* wo       = (const float*)d_in[4];
    const float* router_w = (const float*)d_in[5];
    const float* router_b = (const float*)d_in[6];
    const float* w1       = (const float*)d_in[7];
    const float* w2       = (const float*)d_in[8];
    const float* w3       = (const float*)d_in[9];
    const float* n1s      = (const float*)d_in[10];
    const float* n2s      = (const float*)d_in[11];
    float* out = (float*)d_out;
    unsigned char* ws = (unsigned char*)d_ws;
    const size_t MB = 1ull << 20;

    // Workspace (peak 113 MB, timeline-aliased) — round-4 proven map:
    //  attn phase:  h_bf[0,4) qkv[4,10) wqkvt[10,13) attnb[13,17) wot[17,19)
    //  MoE phase:   grouped_f32[0,32) (zeroed) -> tmp1/hh bf16 [0,32)
    //  persistent:  x2[32,40) h2[40,48) small[48..] grouped_bf[49,65) wtslot[65,97) eout[97,113)
    unsigned short* h_bf  = (unsigned short*)(ws + 0 * MB);
    unsigned short* qkv   = (unsigned short*)(ws + 4 * MB);
    unsigned short* wqkvt = (unsigned short*)(ws + 10 * MB);
    unsigned short* attnb = (unsigned short*)(ws + 13 * MB);
    unsigned short* wot   = (unsigned short*)(ws + 17 * MB);
    float* grouped_f32    = (float*)(ws + 0 * MB);
    unsigned short* tmp1hh = (unsigned short*)(ws + 0 * MB);
    float* x2      = (float*)(ws + 32 * MB);
    float* h2      = (float*)(ws + 40 * MB);
    int*   assign  = (int*)  (ws + 48 * MB);
    int*   pos     = (int*)  (ws + 48 * MB + 65536);
    float* gate    = (float*)(ws + 48 * MB + 131072);
    int*   limit   = (int*)  (ws + 48 * MB + 196608);
    unsigned short* grouped_bf = (unsigned short*)(ws + 49 * MB);
    unsigned short* wtslot     = (unsigned short*)(ws + 65 * MB);
    unsigned short* eout       = (unsigned short*)(ws + 97 * MB);
    (void)in_sizes; (void)n_in; (void)out_size; (void)ws_size;

    // ---- attention half (bf16 MFMA) ----
    transpose_convert<<<dim3(16, 16, 1), 256, 0, stream>>>(wq, wqkvt, Dm, Dm);
    transpose_convert<<<dim3(4, 16, 1), 256, 0, stream>>>(wk, wqkvt + 1024 * 1024, Dm, 256);
    transpose_convert<<<dim3(4, 16, 1), 256, 0, stream>>>(wv, wqkvt + 1280 * 1024, Dm, 256);
    transpose_convert<<<dim3(16, 16, 1), 256, 0, stream>>>(wo, wot, Dm, Dm);
    rmsnorm_bf16_kernel<<<NTOK, 256, 0, stream>>>(x, n1s, h_bf);
    mfma_gemm2<0><<<dim3(QKVS / 128, NTOK / 128), 256, 0, stream>>>(h_bf, wqkvt, qkv, nullptr, QKVS, Dm);
    rope_bf16<<<(NTOK * (HQn + HKVn) * 32) / 256, 256, 0, stream>>>(qkv);
    mfma_attn<<<dim3(Tn / 128, HQn, Bn), 256, 0, stream>>>(qkv, attnb);
    mfma_gemm2<1><<<dim3(Dm / 128, NTOK / 128), 256, 0, stream>>>(attnb, wot, x2, x, Dm, Dm);
    // ---- MoE half ----
    rmsnorm_router_kernel<<<NTOK, 256, 0, stream>>>(x2, n2s, router_w, router_b, h2, assign, gate);
    scan_kernel<<<1, 256, 0, stream>>>(assign, pos, limit);
    hipMemsetAsync(grouped_f32, 0, (size_t)NE * CAPn * Dm * sizeof(float), stream);
    dispatch_kernel<<<NTOK * 2, 256, 0, stream>>>(h2, assign, pos, grouped_f32);
    convert_bf16<<<(NE * CAPn * Dm / 4 + 255) / 256, 256, 0, stream>>>(grouped_f32, grouped_bf, NE * CAPn * Dm / 4);
    // tmp1 = grouped @ w1
    transpose_convert<<<dim3(HIDn / 64, Dm / 64, NE), 256, 0, stream>>>(w1, wtslot, Dm, HIDn);
    mfma_gemm<false><<<dim3(HIDn / 128, CAPn / 128, NE), 256, 0, stream>>>(grouped_bf, wtslot, tmp1hh, HIDn, Dm, limit);
    // hh = gelu((grouped @ w2) * tmp1)
    transpose_convert<<<dim3(HIDn / 64, Dm / 64, NE), 256, 0, stream>>>(w2, wtslot, Dm, HIDn);
    mfma_gemm<true><<<dim3(HIDn / 128, CAPn / 128, NE), 256, 0, stream>>>(grouped_bf, wtslot, tmp1hh, HIDn, Dm, limit);
    // eout = hh @ w3
    transpose_convert<<<dim3(Dm / 64, HIDn / 64, NE), 256, 0, stream>>>(w3, wtslot, HIDn, Dm);
    mfma_gemm<false><<<dim3(Dm / 128, CAPn / 128, NE), 256, 0, stream>>>(tmp1hh, wtslot, eout, Dm, HIDn, limit);
    combine_kernel<<<NTOK, 256, 0, stream>>>(x2, h2, eout, assign, pos, gate, out);
}